// Round 2
// baseline (4076.474 us; speedup 1.0000x reference)
//
#include <hip/hip_runtime.h>
#include <math.h>

#define BB 8
#define NN 1024
#define DD 128
#define HH 2
#define LL 4
#define DFCN 512
#define CAP 128   // max nnz per row/col of adj (mean 51.2, sigma 7 -> P(>128) ~ 0)

// ---------------------------------------------------------------------------
// Generic small-K GEMM: Y[M,NOUT] = X[M,K] @ W[K,NOUT]
// MODE 0: plain row-major in/out
// MODE 1: scatter output [B,N,H*D] -> [B,H,N,D]   (h = relu(c@Wh))
// MODE 2: gather input  [B,H,N,D] -> [B,N,H*D] with relu on load (relu(z)@Wo)
// ---------------------------------------------------------------------------
template<int K, int NOUT, int TM, bool RELU_OUT, int MODE>
__global__ __launch_bounds__(256) void k_gemm(const float* __restrict__ X,
                                              const float* __restrict__ W,
                                              float* __restrict__ Y) {
    constexpr int KC  = 32;
    constexpr int CT  = NOUT / 4;   // col groups (4 cols each)
    constexpr int RT  = 256 / CT;   // row thread groups
    constexpr int RPT = TM / RT;    // rows per thread
    __shared__ float Xs[TM][KC];
    __shared__ float Ws[KC][NOUT];
    const int t   = threadIdx.x;
    const int ct  = t % CT, rt = t / CT;
    const int row0 = blockIdx.x * TM;
    float acc[RPT][4];
#pragma unroll
    for (int r = 0; r < RPT; r++) { acc[r][0]=acc[r][1]=acc[r][2]=acc[r][3]=0.f; }

    for (int k0 = 0; k0 < K; k0 += KC) {
        constexpr int NX4 = TM * KC / 4;
#pragma unroll
        for (int p = 0; p < NX4 / 256; p++) {
            int idx = t + p * 256;
            int r = idx / (KC / 4), kg = idx % (KC / 4);
            int m = row0 + r;
            float4 v;
            if (MODE == 2) {
                int b = m / NN, n = m % NN;
                int hh = k0 / DD;
                int d  = (k0 % DD) + kg * 4;
                v = *(const float4*)&X[(((size_t)b * HH + hh) * NN + n) * DD + d];
                v.x = fmaxf(v.x, 0.f); v.y = fmaxf(v.y, 0.f);
                v.z = fmaxf(v.z, 0.f); v.w = fmaxf(v.w, 0.f);
            } else {
                v = *(const float4*)&X[(size_t)m * K + k0 + kg * 4];
            }
            *(float4*)&Xs[r][kg * 4] = v;
        }
        constexpr int NW4 = KC * NOUT / 4;
#pragma unroll
        for (int p = 0; p < NW4 / 256; p++) {
            int idx = t + p * 256;
            int kk = idx / (NOUT / 4), cg = idx % (NOUT / 4);
            *(float4*)&Ws[kk][cg * 4] =
                *(const float4*)&W[(size_t)(k0 + kk) * NOUT + cg * 4];
        }
        __syncthreads();
#pragma unroll
        for (int kk = 0; kk < KC; kk++) {
            float4 wv = *(const float4*)&Ws[kk][ct * 4];
#pragma unroll
            for (int r = 0; r < RPT; r++) {
                float xv = Xs[rt * RPT + r][kk];
                acc[r][0] += xv * wv.x; acc[r][1] += xv * wv.y;
                acc[r][2] += xv * wv.z; acc[r][3] += xv * wv.w;
            }
        }
        __syncthreads();
    }
#pragma unroll
    for (int r = 0; r < RPT; r++) {
        int m = row0 + rt * RPT + r;
        float4 v = make_float4(acc[r][0], acc[r][1], acc[r][2], acc[r][3]);
        if (RELU_OUT) {
            v.x = fmaxf(v.x, 0.f); v.y = fmaxf(v.y, 0.f);
            v.z = fmaxf(v.z, 0.f); v.w = fmaxf(v.w, 0.f);
        }
        if (MODE == 1) {
            int b = m / NN, n = m % NN;
            int o = ct * 4; int hh = o / DD, d = o % DD;
            *(float4*)&Y[(((size_t)b * HH + hh) * NN + n) * DD + d] = v;
        } else {
            *(float4*)&Y[(size_t)m * NOUT + ct * 4] = v;
        }
    }
}

// ---------------------------------------------------------------------------
// e_sym[bh][j][k] = sum_d hW[bh,j,d]*h[bh,k,d] + hW[bh,k,d]*h[bh,j,d]
// 128x128 tile, 256 threads, 8x8 per thread, d-chunk 16, float4 LDS reads.
// Computed ONCE per layer (branch-independent); only softmax masks differ.
// ---------------------------------------------------------------------------
__global__ __launch_bounds__(256) void k_esym(const float* __restrict__ h,
                                              const float* __restrict__ hW,
                                              float* __restrict__ e) {
    const int bh = blockIdx.z;
    const int j0 = blockIdx.y * 128, k0 = blockIdx.x * 128;
    __shared__ float sHj[16][132], sWj[16][132], sHk[16][132], sWk[16][132];
    const int t = threadIdx.x;
    const int kt = t & 15, jt = t >> 4;
    float acc[8][8];
#pragma unroll
    for (int r = 0; r < 8; r++)
#pragma unroll
        for (int c = 0; c < 8; c++) acc[r][c] = 0.f;

    const float* hb = h  + (size_t)bh * NN * DD;
    const float* wb = hW + (size_t)bh * NN * DD;

    for (int d0 = 0; d0 < DD; d0 += 16) {
        const int kk = t & 15, rr = t >> 4;
#pragma unroll
        for (int p = 0; p < 8; p++) {
            int row = rr + p * 16;
            sHj[kk][row] = hb[(size_t)(j0 + row) * DD + d0 + kk];
            sWj[kk][row] = wb[(size_t)(j0 + row) * DD + d0 + kk];
            sHk[kk][row] = hb[(size_t)(k0 + row) * DD + d0 + kk];
            sWk[kk][row] = wb[(size_t)(k0 + row) * DD + d0 + kk];
        }
        __syncthreads();
#pragma unroll
        for (int kk2 = 0; kk2 < 16; kk2++) {
            const float4 wja = *(const float4*)&sWj[kk2][jt * 8];
            const float4 wjb = *(const float4*)&sWj[kk2][jt * 8 + 4];
            const float4 hja = *(const float4*)&sHj[kk2][jt * 8];
            const float4 hjb = *(const float4*)&sHj[kk2][jt * 8 + 4];
            const float4 wka = *(const float4*)&sWk[kk2][kt * 8];
            const float4 wkb = *(const float4*)&sWk[kk2][kt * 8 + 4];
            const float4 hka = *(const float4*)&sHk[kk2][kt * 8];
            const float4 hkb = *(const float4*)&sHk[kk2][kt * 8 + 4];
            const float wjv[8] = {wja.x,wja.y,wja.z,wja.w, wjb.x,wjb.y,wjb.z,wjb.w};
            const float hjv[8] = {hja.x,hja.y,hja.z,hja.w, hjb.x,hjb.y,hjb.z,hjb.w};
            const float wkv[8] = {wka.x,wka.y,wka.z,wka.w, wkb.x,wkb.y,wkb.z,wkb.w};
            const float hkv[8] = {hka.x,hka.y,hka.z,hka.w, hkb.x,hkb.y,hkb.z,hkb.w};
#pragma unroll
            for (int r = 0; r < 8; r++)
#pragma unroll
                for (int c = 0; c < 8; c++)
                    acc[r][c] += wjv[r] * hkv[c] + wkv[c] * hjv[r];
        }
        __syncthreads();
    }
#pragma unroll
    for (int r = 0; r < 8; r++) {
        int j = j0 + jt * 8 + r;
        float4* dst = (float4*)&e[((size_t)bh * NN + j) * NN + k0 + kt * 8];
        dst[0] = make_float4(acc[r][0], acc[r][1], acc[r][2], acc[r][3]);
        dst[1] = make_float4(acc[r][4], acc[r][5], acc[r][6], acc[r][7]);
    }
}

// ---------------------------------------------------------------------------
// Sparse adjacency build (fixed-stride CSR, CAP slots/row) + column counts.
// Pattern is layer-independent: built once per launch per branch.
// ---------------------------------------------------------------------------
__global__ void k_zero_i(int* __restrict__ p, int n) {
    int g = blockIdx.x * 256 + threadIdx.x;
    if (g < n) p[g] = 0;
}

__global__ void k_build(const float* __restrict__ adj, int* __restrict__ rcur,
                        int* __restrict__ ccnt, int* __restrict__ cidx,
                        float* __restrict__ aval) {
    const int gid = blockIdx.x * 256 + threadIdx.x;  // over B*N*N/4
    const int k4 = (gid & 255) * 4;                  // N/4 = 256
    const int j  = (gid >> 8) & 1023;
    const int b  = gid >> 18;
    const float4 a4 = *(const float4*)&adj[((size_t)b * NN + j) * NN + k4];
    const float av[4] = {a4.x, a4.y, a4.z, a4.w};
#pragma unroll
    for (int i = 0; i < 4; i++) {
        if (av[i] != 0.f) {
            int slot = atomicAdd(&rcur[b * NN + j], 1);
            if (slot < CAP) {
                cidx[((size_t)(b * NN + j)) * CAP + slot] = k4 + i;
                aval[((size_t)(b * NN + j)) * CAP + slot] = av[i];
            }
            atomicAdd(&ccnt[b * NN + k4 + i], 1);
        }
    }
}

// ---------------------------------------------------------------------------
// Sparse masked column-softmax (axis=-2). m_col = max(0, max e_nnz) exactly
// (masked entries contribute exp(0)); denominator adds (N - cnt)*exp(-m).
// P1: gather e -> attv, atomic col max (float-as-int, valid for >=0)
// P2: p = exp(e - m), atomic col sum
// P3: dinv = 1 / (colsum + (N - ccnt) * exp(-m))
// P4: attv = p * adj_val * dinv
// ---------------------------------------------------------------------------
__global__ void k_p1(const float* __restrict__ e, const int* __restrict__ cidx,
                     const int* __restrict__ rcnt, float* __restrict__ attv,
                     int* __restrict__ colmax) {
    const int gid  = blockIdx.x * 256 + threadIdx.x;   // over B*N*CAP
    const int slot = gid & (CAP - 1);
    const int j    = (gid >> 7) & 1023;
    const int b    = gid >> 17;
    if (slot >= min(rcnt[b * NN + j], CAP)) return;
    const int k = cidx[(size_t)gid];
#pragma unroll
    for (int h = 0; h < HH; h++) {
        const int bh = b * HH + h;
        const float ev = e[((size_t)bh * NN + j) * NN + k];
        attv[((size_t)bh * NN + j) * CAP + slot] = ev;
        if (ev > 0.f) atomicMax(&colmax[bh * NN + k], __float_as_int(ev));
    }
}

__global__ void k_p2(const int* __restrict__ cidx, const int* __restrict__ rcnt,
                     float* __restrict__ attv, const int* __restrict__ colmax,
                     float* __restrict__ colsum) {
    const int gid  = blockIdx.x * 256 + threadIdx.x;
    const int slot = gid & (CAP - 1);
    const int j    = (gid >> 7) & 1023;
    const int b    = gid >> 17;
    if (slot >= min(rcnt[b * NN + j], CAP)) return;
    const int k = cidx[(size_t)gid];
#pragma unroll
    for (int h = 0; h < HH; h++) {
        const int bh = b * HH + h;
        const size_t idx = ((size_t)bh * NN + j) * CAP + slot;
        const float m = __int_as_float(colmax[bh * NN + k]);
        const float p = expf(attv[idx] - m);
        attv[idx] = p;
        atomicAdd(&colsum[bh * NN + k], p);
    }
}

__global__ void k_p3(const float* __restrict__ colsum, const int* __restrict__ colmax,
                     const int* __restrict__ ccnt, float* __restrict__ dinv) {
    const int gid = blockIdx.x * 256 + threadIdx.x;   // over B*H*N
    const int k  = gid & 1023;
    const int bh = gid >> 10;
    const int b  = bh >> 1;
    const float m = __int_as_float(colmax[gid]);
    const float denom = colsum[gid] + (float)(NN - ccnt[b * NN + k]) * expf(-m);
    dinv[gid] = 1.f / denom;
}

__global__ void k_p4(const int* __restrict__ cidx, const int* __restrict__ rcnt,
                     const float* __restrict__ aval, const float* __restrict__ dinv,
                     float* __restrict__ attv) {
    const int gid  = blockIdx.x * 256 + threadIdx.x;
    const int slot = gid & (CAP - 1);
    const int j    = (gid >> 7) & 1023;
    const int b    = gid >> 17;
    if (slot >= min(rcnt[b * NN + j], CAP)) return;
    const int k = cidx[(size_t)gid];
    const float a = aval[(size_t)gid];
#pragma unroll
    for (int h = 0; h < HH; h++) {
        const int bh = b * HH + h;
        const size_t idx = ((size_t)bh * NN + j) * CAP + slot;
        attv[idx] = attv[idx] * a * dinv[bh * NN + k];
    }
}

// ---------------------------------------------------------------------------
// Sparse SpMM: out_row = relu(sum_s attv[s] * z[col[s], :]).
// One wave per (bh, row); lanes cover D via float2.
// FUSED: out = beta*h + (1-beta)*relu(att@zin)   (hops >= 1)
// ---------------------------------------------------------------------------
template<bool FUSED>
__global__ __launch_bounds__(256) void k_spmm(const float* __restrict__ attv,
                                              const int* __restrict__ cidx,
                                              const int* __restrict__ rcnt,
                                              const float* __restrict__ zin,
                                              const float* __restrict__ hmat,
                                              const float* __restrict__ beta,
                                              float* __restrict__ out) {
    const int wid  = (blockIdx.x * 256 + threadIdx.x) >> 6;  // bh*N + j
    const int lane = threadIdx.x & 63;
    const int bh = wid >> 10;
    const int j  = wid & 1023;
    const int b  = bh >> 1;
    const int cnt = min(rcnt[b * NN + j], CAP);
    const int*   cp = cidx + ((size_t)(b * NN + j)) * CAP;
    const float* vp = attv + ((size_t)(bh * NN) + j) * CAP;
    const float* zb = zin + (size_t)bh * NN * DD;
    float2 acc = make_float2(0.f, 0.f);
    for (int s = 0; s < cnt; s++) {
        const int   c = cp[s];
        const float v = vp[s];
        const float2 zv = *(const float2*)&zb[(size_t)c * DD + lane * 2];
        acc.x += v * zv.x; acc.y += v * zv.y;
    }
    acc.x = fmaxf(acc.x, 0.f); acc.y = fmaxf(acc.y, 0.f);
    const size_t o = ((size_t)(bh * NN) + j) * DD + lane * 2;
    if (FUSED) {
        const float be = beta[bh * NN + j];
        const float2 hv = *(const float2*)&hmat[o];
        acc.x = be * hv.x + (1.f - be) * acc.x;
        acc.y = be * hv.y + (1.f - be) * acc.y;
    }
    *(float2*)&out[o] = acc;
}

// beta[node] = sigmoid(dot(concat(h,az), Wbw) + bb). One wave per node.
__global__ __launch_bounds__(256) void k_beta(const float* __restrict__ h,
                                              const float* __restrict__ az,
                                              const float* __restrict__ Wbw,
                                              const float* __restrict__ Wbb,
                                              float* __restrict__ beta) {
    const int node = blockIdx.x * 4 + (threadIdx.x >> 6);
    const int lane = threadIdx.x & 63;
    const float* hp = h  + (size_t)node * DD;
    const float* ap = az + (size_t)node * DD;
    float p = hp[lane]      * Wbw[lane]
            + hp[lane + 64] * Wbw[lane + 64]
            + ap[lane]      * Wbw[128 + lane]
            + ap[lane + 64] * Wbw[192 + lane];
#pragma unroll
    for (int off = 32; off > 0; off >>= 1) p += __shfl_down(p, off);
    if (lane == 0) beta[node] = 1.f / (1.f + expf(-(p + Wbb[0])));
}

// z = beta*h + (1-beta)*az (hop 0 only; later hops fuse into k_spmm)
__global__ __launch_bounds__(256) void k_zup(const float* __restrict__ h,
                                             const float* __restrict__ az,
                                             const float* __restrict__ beta,
                                             float* __restrict__ z) {
    const int g = blockIdx.x * 256 + threadIdx.x;      // f4 over B*H*N*D/4
    const float be = beta[g >> 5];
    const float4 hv = ((const float4*)h)[g];
    const float4 av = ((const float4*)az)[g];
    float4 o;
    o.x = be * hv.x + (1.f - be) * av.x;
    o.y = be * hv.y + (1.f - be) * av.y;
    o.z = be * hv.z + (1.f - be) * av.z;
    o.w = be * hv.w + (1.f - be) * av.w;
    ((float4*)z)[g] = o;
}

__global__ __launch_bounds__(256) void k_sub(const float* __restrict__ c2,
                                             const float* __restrict__ c1,
                                             float* __restrict__ c) {
    const int g = blockIdx.x * 256 + threadIdx.x;
    const float4 a = ((const float4*)c2)[g];
    const float4 b = ((const float4*)c1)[g];
    ((float4*)c)[g] = make_float4(a.x - b.x, a.y - b.y, a.z - b.z, a.w - b.w);
}

__global__ void k_pool(const float* __restrict__ c, const float* __restrict__ valid,
                       float* __restrict__ pooled) {
    const int b = blockIdx.x, d = threadIdx.x;     // 128 threads
    const float* cb = c + (size_t)b * NN * DD;
    const float* vb = valid + (size_t)b * NN;
    float s = 0.f, sv = 0.f;
    for (int n = 0; n < NN; n++) { float v = vb[n]; s += cb[(size_t)n * DD + d] * v; sv += v; }
    pooled[b * DD + d] = s / sv;
}

template<int K, int NOUT, bool RELU>
__global__ void k_fc(const float* __restrict__ X, const float* __restrict__ W,
                     const float* __restrict__ bias, float* __restrict__ Y) {
    const int gid = blockIdx.x * blockDim.x + threadIdx.x;
    if (gid >= BB * NOUT) return;
    const int b = gid / NOUT, o = gid % NOUT;
    float s = bias[o];
    for (int i = 0; i < K; i++) s += X[(size_t)b * K + i] * W[(size_t)i * NOUT + o];
    Y[gid] = RELU ? fmaxf(s, 0.f) : s;
}

__global__ void k_fc2(const float* __restrict__ X, const float* __restrict__ W,
                      const float* __restrict__ bias, float* __restrict__ out) {
    const int b = threadIdx.x >> 6, lane = threadIdx.x & 63;
    float s = 0.f;
    for (int i = lane; i < DFCN; i += 64) s += X[(size_t)b * DFCN + i] * W[i];
#pragma unroll
    for (int off = 32; off > 0; off >>= 1) s += __shfl_down(s, off);
    if (lane == 0) out[b] = 1.f / (1.f + expf(-(s + bias[0])));
}

// ---------------------------------------------------------------------------
extern "C" void kernel_launch(void* const* d_in, const int* in_sizes, int n_in,
                              void* d_out, int out_size, void* d_ws, size_t ws_size,
                              hipStream_t stream) {
    const float* x        = (const float*)d_in[0];
    const float* adj1     = (const float*)d_in[1];
    const float* adj2     = (const float*)d_in[2];
    const float* valid    = (const float*)d_in[3];
    const float* embede_w = (const float*)d_in[4];
    const float* Wh       = (const float*)d_in[5];   // [L,128,256]
    const float* We       = (const float*)d_in[6];   // [L,128,128]
    const float* Wbw      = (const float*)d_in[7];   // [L,256]
    const float* Wbb      = (const float*)d_in[8];   // [L]
    const float* Wo       = (const float*)d_in[9];   // [L,256,128]
    const float* fc0_w    = (const float*)d_in[10];
    const float* fc0_b    = (const float*)d_in[11];
    const float* fc1_w    = (const float*)d_in[12];
    const float* fc1_b    = (const float*)d_in[13];
    const float* fc2_w    = (const float*)d_in[14];
    const float* fc2_b    = (const float*)d_in[15];

    // ---- workspace carve (float units; total ~36.8M floats ~ 147MB) ----
    float* ws = (float*)d_ws;
    float* c      = ws;                          // 1,048,576
    float* h      = c      + (size_t)1048576;    // 2,097,152
    float* hW     = h      + (size_t)2097152;    // 2,097,152
    float* z      = hW     + (size_t)2097152;    // 2,097,152
    float* z2     = z      + (size_t)2097152;    // 2,097,152
    float* az     = z2     + (size_t)2097152;    // 2,097,152
    float* beta   = az     + (size_t)2097152;    // 16,384
    float* c1     = beta   + (size_t)16384;      // 1,048,576
    float* c2     = c1     + (size_t)1048576;    // 1,048,576
    float* pooled = c2     + (size_t)1048576;    // 1,024
    float* f0     = pooled + (size_t)1024;       // 4,096
    float* f1     = f0     + (size_t)4096;       // 4,096
    float* attv   = f1     + (size_t)4096;       // B*H*N*CAP = 2,097,152
    float* e      = attv   + (size_t)2097152;    // B*H*N*N   = 16,777,216
    int*   cidx1  = (int*)(e + (size_t)16777216); // B*N*CAP = 1,048,576 ints
    float* aval1  = (float*)(cidx1 + (size_t)1048576);
    int*   cidx2  = (int*)(aval1 + (size_t)1048576);
    float* aval2  = (float*)(cidx2 + (size_t)1048576);
    int*   rcnt1  = (int*)(aval2 + (size_t)1048576); // 8,192
    int*   ccnt1  = rcnt1 + 8192;
    int*   rcnt2  = ccnt1 + 8192;
    int*   ccnt2  = rcnt2 + 8192;                    // rcnt1..ccnt2 contiguous 32768
    int*   colmax = ccnt2 + 8192;                    // B*H*N = 16,384 (float bits)
    float* colsum = (float*)(colmax + 16384);        // 16,384
    float* dinv   = colsum + 16384;                  // 16,384

    // ---- build sparse structures (pattern is layer-independent) ----
    k_zero_i<<<128, 256, 0, stream>>>(rcnt1, 32768);              // rcnt1,ccnt1,rcnt2,ccnt2
    k_build<<<8192, 256, 0, stream>>>(adj1, rcnt1, ccnt1, cidx1, aval1);
    k_build<<<8192, 256, 0, stream>>>(adj2, rcnt2, ccnt2, cidx2, aval2);

    // c = x @ embede_w
    k_gemm<128,128,64,false,0><<<128, 256, 0, stream>>>(x, embede_w, c);

    for (int k = 0; k < LL; k++) {
        const int nhop = k + 1;
        // h = relu(c @ Wh[k]) scattered to [B,H,N,D]
        k_gemm<128,256,32,true,1><<<256, 256, 0, stream>>>(c, Wh + (size_t)k*128*256, h);
        // hW = h @ We[k]
        k_gemm<128,128,64,false,0><<<256, 256, 0, stream>>>(h, We + (size_t)k*128*128, hW);
        // dense symmetric e (shared by both branches)
        k_esym<<<dim3(8,8,16), 256, 0, stream>>>(h, hW, e);

        for (int br = 0; br < 2; br++) {
            const int*   cidx = (br == 0) ? cidx1 : cidx2;
            const float* aval = (br == 0) ? aval1 : aval2;
            const int*   rcnt = (br == 0) ? rcnt1 : rcnt2;
            const int*   ccnt = (br == 0) ? ccnt1 : ccnt2;
            float*       cb   = (br == 0) ? c1    : c2;

            // sparse softmax over columns
            k_zero_i<<<128, 256, 0, stream>>>(colmax, 32768);  // colmax + colsum
            k_p1<<<4096, 256, 0, stream>>>(e, cidx, rcnt, attv, colmax);
            k_p2<<<4096, 256, 0, stream>>>(cidx, rcnt, attv, colmax, colsum);
            k_p3<<<64, 256, 0, stream>>>(colsum, colmax, ccnt, dinv);
            k_p4<<<4096, 256, 0, stream>>>(cidx, rcnt, aval, dinv, attv);

            // hop 0: az = relu(att@h); beta; z = beta*h + (1-beta)*az
            k_spmm<false><<<4096, 256, 0, stream>>>(attv, cidx, rcnt, h, nullptr, nullptr, az);
            k_beta<<<4096, 256, 0, stream>>>(h, az, Wbw + (size_t)k*256, Wbb + k, beta);
            k_zup<<<2048, 256, 0, stream>>>(h, az, beta, z);
            // hops 1..nhop-1 fused
            float* zA = z; float* zB = z2;
            for (int t = 1; t < nhop; t++) {
                k_spmm<true><<<4096, 256, 0, stream>>>(attv, cidx, rcnt, zA, h, beta, zB);
                float* tmp = zA; zA = zB; zB = tmp;
            }
            // cb = relu(z gathered to [B,N,H*D]) @ Wo[k]
            k_gemm<256,128,64,false,2><<<128, 256, 0, stream>>>(zA, Wo + (size_t)k*256*128, cb);
        }
        k_sub<<<1024, 256, 0, stream>>>(c2, c1, c);
    }

    k_pool<<<8, 128, 0, stream>>>(c, valid, pooled);
    k_fc<128, DFCN, true><<<16, 256, 0, stream>>>(pooled, fc0_w, fc0_b, f0);
    k_fc<DFCN, DFCN, true><<<16, 256, 0, stream>>>(f0, fc1_w, fc1_b, f1);
    k_fc2<<<1, 512, 0, stream>>>(f1, fc2_w, fc2_b, (float*)d_out);
}

// Round 3
// 2930.784 us; speedup vs baseline: 1.3909x; 1.3909x over previous
//
#include <hip/hip_runtime.h>
#include <math.h>

#define BB 8
#define NN 1024
#define DD 128
#define HH 2
#define LL 4
#define DFCN 512
#define CAP 128   // max nnz per row/col of adj (mean 51.2, sigma 7 -> P(>128) ~ 0)

typedef __attribute__((ext_vector_type(8))) short bf16x8;
typedef __attribute__((ext_vector_type(4))) float f32x4;

// fp32 -> bf16 (RNE) and back, bit ops only
static __device__ __forceinline__ unsigned short f2bf(float f) {
    unsigned u = __float_as_uint(f);
    u += 0x7FFF + ((u >> 16) & 1);
    return (unsigned short)(u >> 16);
}
static __device__ __forceinline__ float bf2f(unsigned short s) {
    return __uint_as_float(((unsigned)s) << 16);
}

// ---------------------------------------------------------------------------
// Generic small-K GEMM: Y[M,NOUT] = X[M,K] @ W[K,NOUT]
// MODE 0: plain row-major in/out
// MODE 1: scatter output [B,N,H*D] -> [B,H,N,D]   (h = relu(c@Wh))
// MODE 2: gather input  [B,H,N,D] -> [B,N,H*D] with relu on load (relu(z)@Wo)
// ---------------------------------------------------------------------------
template<int K, int NOUT, int TM, bool RELU_OUT, int MODE>
__global__ __launch_bounds__(256) void k_gemm(const float* __restrict__ X,
                                              const float* __restrict__ W,
                                              float* __restrict__ Y) {
    constexpr int KC  = 32;
    constexpr int CT  = NOUT / 4;   // col groups (4 cols each)
    constexpr int RT  = 256 / CT;   // row thread groups
    constexpr int RPT = TM / RT;    // rows per thread
    __shared__ float Xs[TM][KC];
    __shared__ float Ws[KC][NOUT];
    const int t   = threadIdx.x;
    const int ct  = t % CT, rt = t / CT;
    const int row0 = blockIdx.x * TM;
    float acc[RPT][4];
#pragma unroll
    for (int r = 0; r < RPT; r++) { acc[r][0]=acc[r][1]=acc[r][2]=acc[r][3]=0.f; }

    for (int k0 = 0; k0 < K; k0 += KC) {
        constexpr int NX4 = TM * KC / 4;
#pragma unroll
        for (int p = 0; p < NX4 / 256; p++) {
            int idx = t + p * 256;
            int r = idx / (KC / 4), kg = idx % (KC / 4);
            int m = row0 + r;
            float4 v;
            if (MODE == 2) {
                int b = m / NN, n = m % NN;
                int hh = k0 / DD;
                int d  = (k0 % DD) + kg * 4;
                v = *(const float4*)&X[(((size_t)b * HH + hh) * NN + n) * DD + d];
                v.x = fmaxf(v.x, 0.f); v.y = fmaxf(v.y, 0.f);
                v.z = fmaxf(v.z, 0.f); v.w = fmaxf(v.w, 0.f);
            } else {
                v = *(const float4*)&X[(size_t)m * K + k0 + kg * 4];
            }
            *(float4*)&Xs[r][kg * 4] = v;
        }
        constexpr int NW4 = KC * NOUT / 4;
#pragma unroll
        for (int p = 0; p < NW4 / 256; p++) {
            int idx = t + p * 256;
            int kk = idx / (NOUT / 4), cg = idx % (NOUT / 4);
            *(float4*)&Ws[kk][cg * 4] =
                *(const float4*)&W[(size_t)(k0 + kk) * NOUT + cg * 4];
        }
        __syncthreads();
#pragma unroll
        for (int kk = 0; kk < KC; kk++) {
            float4 wv = *(const float4*)&Ws[kk][ct * 4];
#pragma unroll
            for (int r = 0; r < RPT; r++) {
                float xv = Xs[rt * RPT + r][kk];
                acc[r][0] += xv * wv.x; acc[r][1] += xv * wv.y;
                acc[r][2] += xv * wv.z; acc[r][3] += xv * wv.w;
            }
        }
        __syncthreads();
    }
#pragma unroll
    for (int r = 0; r < RPT; r++) {
        int m = row0 + rt * RPT + r;
        float4 v = make_float4(acc[r][0], acc[r][1], acc[r][2], acc[r][3]);
        if (RELU_OUT) {
            v.x = fmaxf(v.x, 0.f); v.y = fmaxf(v.y, 0.f);
            v.z = fmaxf(v.z, 0.f); v.w = fmaxf(v.w, 0.f);
        }
        if (MODE == 1) {
            int b = m / NN, n = m % NN;
            int o = ct * 4; int hh = o / DD, d = o % DD;
            *(float4*)&Y[(((size_t)b * HH + hh) * NN + n) * DD + d] = v;
        } else {
            *(float4*)&Y[(size_t)m * NOUT + ct * 4] = v;
        }
    }
}

// ---------------------------------------------------------------------------
// Split h, hW (f32 [BH,N,D]) into hi/lo bf16 arrays (Markidis split).
// ---------------------------------------------------------------------------
__global__ __launch_bounds__(256) void k_split(const float* __restrict__ h,
                                               const float* __restrict__ hW,
                                               ushort* __restrict__ hHi, ushort* __restrict__ hLo,
                                               ushort* __restrict__ wHi, ushort* __restrict__ wLo) {
    const int g = blockIdx.x * 256 + threadIdx.x;   // over BH*N*D/4 = 524288
    float4 v = ((const float4*)h)[g];
    ushort4 hi, lo;
    hi.x = f2bf(v.x); lo.x = f2bf(v.x - bf2f(hi.x));
    hi.y = f2bf(v.y); lo.y = f2bf(v.y - bf2f(hi.y));
    hi.z = f2bf(v.z); lo.z = f2bf(v.z - bf2f(hi.z));
    hi.w = f2bf(v.w); lo.w = f2bf(v.w - bf2f(hi.w));
    ((ushort4*)hHi)[g] = hi; ((ushort4*)hLo)[g] = lo;
    v = ((const float4*)hW)[g];
    hi.x = f2bf(v.x); lo.x = f2bf(v.x - bf2f(hi.x));
    hi.y = f2bf(v.y); lo.y = f2bf(v.y - bf2f(hi.y));
    hi.z = f2bf(v.z); lo.z = f2bf(v.z - bf2f(hi.z));
    hi.w = f2bf(v.w); lo.w = f2bf(v.w - bf2f(hi.w));
    ((ushort4*)wHi)[g] = hi; ((ushort4*)wLo)[g] = lo;
}

// ---------------------------------------------------------------------------
// e[j,k] = hW_j.h_k + h_j.hW_k  via split-bf16 MFMA (6 terms, lo*lo dropped).
// 128x128 tile / block, 4 waves (each a 64x64 quadrant, 4x4 frags of 16x16).
// BK=32 (one mfma K per chunk). LDS rows padded to 40 bf16 (80B: 20*row mod 32
// has period 8 -> ds_read_b128 is 2-way = conflict-free).
// e is symmetric, so any operand/CD transpose confusion self-heals.
// ---------------------------------------------------------------------------
__global__ __launch_bounds__(256) void k_esym_mfma(const ushort* __restrict__ wHi,
                                                   const ushort* __restrict__ wLo,
                                                   const ushort* __restrict__ hHi,
                                                   const ushort* __restrict__ hLo,
                                                   float* __restrict__ e) {
    __shared__ ushort sWjHi[128*40], sWjLo[128*40], sHjHi[128*40], sHjLo[128*40];
    __shared__ ushort sWkHi[128*40], sWkLo[128*40], sHkHi[128*40], sHkLo[128*40];
    const int bh = blockIdx.z;
    const int j0 = blockIdx.y * 128, k0 = blockIdx.x * 128;
    const int t = threadIdx.x;
    const int wave = t >> 6, lane = t & 63;
    const int wr = wave >> 1, wc = wave & 1;
    const int lrow = lane & 15, lg = lane >> 4;

    f32x4 acc[4][4];
#pragma unroll
    for (int m = 0; m < 4; m++)
#pragma unroll
        for (int n = 0; n < 4; n++) {
            acc[m][n][0] = 0.f; acc[m][n][1] = 0.f;
            acc[m][n][2] = 0.f; acc[m][n][3] = 0.f;
        }

    const size_t bhbase = (size_t)bh * NN * DD;

    for (int d0 = 0; d0 < DD; d0 += 32) {
        __syncthreads();
        // stage one [128][32] bf16 tile per (matrix, side): 2x 16B units/thread
#define STAGE2(SRC, DST, BASE)                                                   \
        {                                                                        \
            _Pragma("unroll")                                                    \
            for (int q = 0; q < 2; q++) {                                        \
                const int u = t + q * 256;                                       \
                const int row = u >> 2, cu = (u & 3) * 8;                        \
                *(uint4*)&DST[row * 40 + cu] =                                   \
                    *(const uint4*)&SRC[bhbase + (size_t)(BASE + row) * DD + d0 + cu]; \
            }                                                                    \
        }
        STAGE2(wHi, sWjHi, j0) STAGE2(wLo, sWjLo, j0)
        STAGE2(hHi, sHjHi, j0) STAGE2(hLo, sHjLo, j0)
        STAGE2(wHi, sWkHi, k0) STAGE2(wLo, sWkLo, k0)
        STAGE2(hHi, sHkHi, k0) STAGE2(hLo, sHkLo, k0)
#undef STAGE2
        __syncthreads();

        bf16x8 a0[4], a1[4], b0[4], b1[4];
        // ---- group 1: A = hW_j, B = h_k ----
#pragma unroll
        for (int m = 0; m < 4; m++) {
            const int off = (wr * 64 + m * 16 + lrow) * 40 + lg * 8;
            a0[m] = *(const bf16x8*)&sWjHi[off];
            a1[m] = *(const bf16x8*)&sWjLo[off];
        }
#pragma unroll
        for (int n = 0; n < 4; n++) {
            const int off = (wc * 64 + n * 16 + lrow) * 40 + lg * 8;
            b0[n] = *(const bf16x8*)&sHkHi[off];
            b1[n] = *(const bf16x8*)&sHkLo[off];
        }
#pragma unroll
        for (int m = 0; m < 4; m++)
#pragma unroll
            for (int n = 0; n < 4; n++) {
                acc[m][n] = __builtin_amdgcn_mfma_f32_16x16x32_bf16(a0[m], b0[n], acc[m][n], 0, 0, 0);
                acc[m][n] = __builtin_amdgcn_mfma_f32_16x16x32_bf16(a0[m], b1[n], acc[m][n], 0, 0, 0);
                acc[m][n] = __builtin_amdgcn_mfma_f32_16x16x32_bf16(a1[m], b0[n], acc[m][n], 0, 0, 0);
            }
        // ---- group 2: A = h_j, B = hW_k ----
#pragma unroll
        for (int m = 0; m < 4; m++) {
            const int off = (wr * 64 + m * 16 + lrow) * 40 + lg * 8;
            a0[m] = *(const bf16x8*)&sHjHi[off];
            a1[m] = *(const bf16x8*)&sHjLo[off];
        }
#pragma unroll
        for (int n = 0; n < 4; n++) {
            const int off = (wc * 64 + n * 16 + lrow) * 40 + lg * 8;
            b0[n] = *(const bf16x8*)&sWkHi[off];
            b1[n] = *(const bf16x8*)&sWkLo[off];
        }
#pragma unroll
        for (int m = 0; m < 4; m++)
#pragma unroll
            for (int n = 0; n < 4; n++) {
                acc[m][n] = __builtin_amdgcn_mfma_f32_16x16x32_bf16(a0[m], b0[n], acc[m][n], 0, 0, 0);
                acc[m][n] = __builtin_amdgcn_mfma_f32_16x16x32_bf16(a0[m], b1[n], acc[m][n], 0, 0, 0);
                acc[m][n] = __builtin_amdgcn_mfma_f32_16x16x32_bf16(a1[m], b0[n], acc[m][n], 0, 0, 0);
            }
    }

    // C/D layout (m89-verified): col = lane&15, row = (lane>>4)*4 + reg
#pragma unroll
    for (int m = 0; m < 4; m++)
#pragma unroll
        for (int n = 0; n < 4; n++) {
            const int r = j0 + wr * 64 + m * 16 + lg * 4;
            const int cc = k0 + wc * 64 + n * 16 + lrow;
            float* dst = &e[((size_t)bh * NN + r) * NN + cc];
#pragma unroll
            for (int q = 0; q < 4; q++) dst[(size_t)q * NN] = acc[m][n][q];
        }
}

// ---------------------------------------------------------------------------
// Sparse adjacency build (fixed-stride CSR, CAP slots/row) + column counts.
// ---------------------------------------------------------------------------
__global__ void k_zero_i(int* __restrict__ p, int n) {
    int g = blockIdx.x * 256 + threadIdx.x;
    if (g < n) p[g] = 0;
}

__global__ void k_build(const float* __restrict__ adj, int* __restrict__ rcur,
                        int* __restrict__ ccnt, int* __restrict__ cidx,
                        float* __restrict__ aval) {
    const int gid = blockIdx.x * 256 + threadIdx.x;  // over B*N*N/4
    const int k4 = (gid & 255) * 4;                  // N/4 = 256
    const int j  = (gid >> 8) & 1023;
    const int b  = gid >> 18;
    const float4 a4 = *(const float4*)&adj[((size_t)b * NN + j) * NN + k4];
    const float av[4] = {a4.x, a4.y, a4.z, a4.w};
#pragma unroll
    for (int i = 0; i < 4; i++) {
        if (av[i] != 0.f) {
            int slot = atomicAdd(&rcur[b * NN + j], 1);
            if (slot < CAP) {
                cidx[((size_t)(b * NN + j)) * CAP + slot] = k4 + i;
                aval[((size_t)(b * NN + j)) * CAP + slot] = av[i];
            }
            atomicAdd(&ccnt[b * NN + k4 + i], 1);
        }
    }
}

// ---------------------------------------------------------------------------
// Sparse masked column-softmax (axis=-2). m_col = max(0, max e_nnz) exactly.
// ---------------------------------------------------------------------------
__global__ void k_p1(const float* __restrict__ e, const int* __restrict__ cidx,
                     const int* __restrict__ rcnt, float* __restrict__ attv,
                     int* __restrict__ colmax) {
    const int gid  = blockIdx.x * 256 + threadIdx.x;   // over B*N*CAP
    const int slot = gid & (CAP - 1);
    const int j    = (gid >> 7) & 1023;
    const int b    = gid >> 17;
    if (slot >= min(rcnt[b * NN + j], CAP)) return;
    const int k = cidx[(size_t)gid];
#pragma unroll
    for (int h = 0; h < HH; h++) {
        const int bh = b * HH + h;
        const float ev = e[((size_t)bh * NN + j) * NN + k];
        attv[((size_t)bh * NN + j) * CAP + slot] = ev;
        if (ev > 0.f) atomicMax(&colmax[bh * NN + k], __float_as_int(ev));
    }
}

__global__ void k_p2(const int* __restrict__ cidx, const int* __restrict__ rcnt,
                     float* __restrict__ attv, const int* __restrict__ colmax,
                     float* __restrict__ colsum) {
    const int gid  = blockIdx.x * 256 + threadIdx.x;
    const int slot = gid & (CAP - 1);
    const int j    = (gid >> 7) & 1023;
    const int b    = gid >> 17;
    if (slot >= min(rcnt[b * NN + j], CAP)) return;
    const int k = cidx[(size_t)gid];
#pragma unroll
    for (int h = 0; h < HH; h++) {
        const int bh = b * HH + h;
        const size_t idx = ((size_t)bh * NN + j) * CAP + slot;
        const float m = __int_as_float(colmax[bh * NN + k]);
        const float p = expf(attv[idx] - m);
        attv[idx] = p;
        atomicAdd(&colsum[bh * NN + k], p);
    }
}

__global__ void k_p3(const float* __restrict__ colsum, const int* __restrict__ colmax,
                     const int* __restrict__ ccnt, float* __restrict__ dinv) {
    const int gid = blockIdx.x * 256 + threadIdx.x;   // over B*H*N
    const int k  = gid & 1023;
    const int bh = gid >> 10;
    const int b  = bh >> 1;
    const float m = __int_as_float(colmax[gid]);
    const float denom = colsum[gid] + (float)(NN - ccnt[b * NN + k]) * expf(-m);
    dinv[gid] = 1.f / denom;
}

__global__ void k_p4(const int* __restrict__ cidx, const int* __restrict__ rcnt,
                     const float* __restrict__ aval, const float* __restrict__ dinv,
                     float* __restrict__ attv) {
    const int gid  = blockIdx.x * 256 + threadIdx.x;
    const int slot = gid & (CAP - 1);
    const int j    = (gid >> 7) & 1023;
    const int b    = gid >> 17;
    if (slot >= min(rcnt[b * NN + j], CAP)) return;
    const int k = cidx[(size_t)gid];
    const float a = aval[(size_t)gid];
#pragma unroll
    for (int h = 0; h < HH; h++) {
        const int bh = b * HH + h;
        const size_t idx = ((size_t)bh * NN + j) * CAP + slot;
        attv[idx] = attv[idx] * a * dinv[bh * NN + k];
    }
}

// ---------------------------------------------------------------------------
// Sparse SpMM: out_row = relu(sum_s attv[s] * z[col[s], :]).
// FUSED: out = beta*h + (1-beta)*relu(att@zin)   (hops >= 1)
// ---------------------------------------------------------------------------
template<bool FUSED>
__global__ __launch_bounds__(256) void k_spmm(const float* __restrict__ attv,
                                              const int* __restrict__ cidx,
                                              const int* __restrict__ rcnt,
                                              const float* __restrict__ zin,
                                              const float* __restrict__ hmat,
                                              const float* __restrict__ beta,
                                              float* __restrict__ out) {
    const int wid  = (blockIdx.x * 256 + threadIdx.x) >> 6;  // bh*N + j
    const int lane = threadIdx.x & 63;
    const int bh = wid >> 10;
    const int j  = wid & 1023;
    const int b  = bh >> 1;
    const int cnt = min(rcnt[b * NN + j], CAP);
    const int*   cp = cidx + ((size_t)(b * NN + j)) * CAP;
    const float* vp = attv + ((size_t)(bh * NN) + j) * CAP;
    const float* zb = zin + (size_t)bh * NN * DD;
    float2 acc = make_float2(0.f, 0.f);
    for (int s = 0; s < cnt; s++) {
        const int   c = cp[s];
        const float v = vp[s];
        const float2 zv = *(const float2*)&zb[(size_t)c * DD + lane * 2];
        acc.x += v * zv.x; acc.y += v * zv.y;
    }
    acc.x = fmaxf(acc.x, 0.f); acc.y = fmaxf(acc.y, 0.f);
    const size_t o = ((size_t)(bh * NN) + j) * DD + lane * 2;
    if (FUSED) {
        const float be = beta[bh * NN + j];
        const float2 hv = *(const float2*)&hmat[o];
        acc.x = be * hv.x + (1.f - be) * acc.x;
        acc.y = be * hv.y + (1.f - be) * acc.y;
    }
    *(float2*)&out[o] = acc;
}

// beta[node] = sigmoid(dot(concat(h,az), Wbw) + bb). One wave per node.
__global__ __launch_bounds__(256) void k_beta(const float* __restrict__ h,
                                              const float* __restrict__ az,
                                              const float* __restrict__ Wbw,
                                              const float* __restrict__ Wbb,
                                              float* __restrict__ beta) {
    const int node = blockIdx.x * 4 + (threadIdx.x >> 6);
    const int lane = threadIdx.x & 63;
    const float* hp = h  + (size_t)node * DD;
    const float* ap = az + (size_t)node * DD;
    float p = hp[lane]      * Wbw[lane]
            + hp[lane + 64] * Wbw[lane + 64]
            + ap[lane]      * Wbw[128 + lane]
            + ap[lane + 64] * Wbw[192 + lane];
#pragma unroll
    for (int off = 32; off > 0; off >>= 1) p += __shfl_down(p, off);
    if (lane == 0) beta[node] = 1.f / (1.f + expf(-(p + Wbb[0])));
}

// z = beta*h + (1-beta)*az (hop 0 only; later hops fuse into k_spmm)
__global__ __launch_bounds__(256) void k_zup(const float* __restrict__ h,
                                             const float* __restrict__ az,
                                             const float* __restrict__ beta,
                                             float* __restrict__ z) {
    const int g = blockIdx.x * 256 + threadIdx.x;      // f4 over B*H*N*D/4
    const float be = beta[g >> 5];
    const float4 hv = ((const float4*)h)[g];
    const float4 av = ((const float4*)az)[g];
    float4 o;
    o.x = be * hv.x + (1.f - be) * av.x;
    o.y = be * hv.y + (1.f - be) * av.y;
    o.z = be * hv.z + (1.f - be) * av.z;
    o.w = be * hv.w + (1.f - be) * av.w;
    ((float4*)z)[g] = o;
}

__global__ __launch_bounds__(256) void k_sub(const float* __restrict__ c2,
                                             const float* __restrict__ c1,
                                             float* __restrict__ c) {
    const int g = blockIdx.x * 256 + threadIdx.x;
    const float4 a = ((const float4*)c2)[g];
    const float4 b = ((const float4*)c1)[g];
    ((float4*)c)[g] = make_float4(a.x - b.x, a.y - b.y, a.z - b.z, a.w - b.w);
}

__global__ void k_pool(const float* __restrict__ c, const float* __restrict__ valid,
                       float* __restrict__ pooled) {
    const int b = blockIdx.x, d = threadIdx.x;     // 128 threads
    const float* cb = c + (size_t)b * NN * DD;
    const float* vb = valid + (size_t)b * NN;
    float s = 0.f, sv = 0.f;
    for (int n = 0; n < NN; n++) { float v = vb[n]; s += cb[(size_t)n * DD + d] * v; sv += v; }
    pooled[b * DD + d] = s / sv;
}

template<int K, int NOUT, bool RELU>
__global__ void k_fc(const float* __restrict__ X, const float* __restrict__ W,
                     const float* __restrict__ bias, float* __restrict__ Y) {
    const int gid = blockIdx.x * blockDim.x + threadIdx.x;
    if (gid >= BB * NOUT) return;
    const int b = gid / NOUT, o = gid % NOUT;
    float s = bias[o];
    for (int i = 0; i < K; i++) s += X[(size_t)b * K + i] * W[(size_t)i * NOUT + o];
    Y[gid] = RELU ? fmaxf(s, 0.f) : s;
}

__global__ void k_fc2(const float* __restrict__ X, const float* __restrict__ W,
                      const float* __restrict__ bias, float* __restrict__ out) {
    const int b = threadIdx.x >> 6, lane = threadIdx.x & 63;
    float s = 0.f;
    for (int i = lane; i < DFCN; i += 64) s += X[(size_t)b * DFCN + i] * W[i];
#pragma unroll
    for (int off = 32; off > 0; off >>= 1) s += __shfl_down(s, off);
    if (lane == 0) out[b] = 1.f / (1.f + expf(-(s + bias[0])));
}

// ---------------------------------------------------------------------------
extern "C" void kernel_launch(void* const* d_in, const int* in_sizes, int n_in,
                              void* d_out, int out_size, void* d_ws, size_t ws_size,
                              hipStream_t stream) {
    const float* x        = (const float*)d_in[0];
    const float* adj1     = (const float*)d_in[1];
    const float* adj2     = (const float*)d_in[2];
    const float* valid    = (const float*)d_in[3];
    const float* embede_w = (const float*)d_in[4];
    const float* Wh       = (const float*)d_in[5];   // [L,128,256]
    const float* We       = (const float*)d_in[6];   // [L,128,128]
    const float* Wbw      = (const float*)d_in[7];   // [L,256]
    const float* Wbb      = (const float*)d_in[8];   // [L]
    const float* Wo       = (const float*)d_in[9];   // [L,256,128]
    const float* fc0_w    = (const float*)d_in[10];
    const float* fc0_b    = (const float*)d_in[11];
    const float* fc1_w    = (const float*)d_in[12];
    const float* fc1_b    = (const float*)d_in[13];
    const float* fc2_w    = (const float*)d_in[14];
    const float* fc2_b    = (const float*)d_in[15];

    // ---- workspace carve (float units; total ~41M floats ~ 164MB) ----
    float* ws = (float*)d_ws;
    float* c      = ws;                          // 1,048,576
    float* h      = c      + (size_t)1048576;    // 2,097,152
    float* hW     = h      + (size_t)2097152;    // 2,097,152
    float* z      = hW     + (size_t)2097152;    // 2,097,152
    float* z2     = z      + (size_t)2097152;    // 2,097,152
    float* az     = z2     + (size_t)2097152;    // 2,097,152
    float* beta   = az     + (size_t)2097152;    // 16,384
    float* c1     = beta   + (size_t)16384;      // 1,048,576
    float* c2     = c1     + (size_t)1048576;    // 1,048,576
    float* pooled = c2     + (size_t)1048576;    // 1,024
    float* f0     = pooled + (size_t)1024;       // 4,096
    float* f1     = f0     + (size_t)4096;       // 4,096
    float* attv   = f1     + (size_t)4096;       // B*H*N*CAP = 2,097,152
    float* e      = attv   + (size_t)2097152;    // B*H*N*N   = 16,777,216
    int*   cidx1  = (int*)(e + (size_t)16777216); // B*N*CAP = 1,048,576 ints
    float* aval1  = (float*)(cidx1 + (size_t)1048576);
    int*   cidx2  = (int*)(aval1 + (size_t)1048576);
    float* aval2  = (float*)(cidx2 + (size_t)1048576);
    int*   rcnt1  = (int*)(aval2 + (size_t)1048576); // 8,192
    int*   ccnt1  = rcnt1 + 8192;
    int*   rcnt2  = ccnt1 + 8192;
    int*   ccnt2  = rcnt2 + 8192;                    // rcnt1..ccnt2 contiguous 32768
    int*   colmax = ccnt2 + 8192;                    // B*H*N = 16,384 (float bits)
    float* colsum = (float*)(colmax + 16384);        // 16,384
    float* dinv   = colsum + 16384;                  // 16,384
    // bf16 split arrays: 4 x BH*N*D ushorts (4 MB each)
    ushort* hHi = (ushort*)(dinv + 16384);
    ushort* hLo = hHi + (size_t)2097152;
    ushort* wHi = hLo + (size_t)2097152;
    ushort* wLo = wHi + (size_t)2097152;

    // ---- build sparse structures (pattern is layer-independent) ----
    k_zero_i<<<128, 256, 0, stream>>>(rcnt1, 32768);              // rcnt1,ccnt1,rcnt2,ccnt2
    k_build<<<8192, 256, 0, stream>>>(adj1, rcnt1, ccnt1, cidx1, aval1);
    k_build<<<8192, 256, 0, stream>>>(adj2, rcnt2, ccnt2, cidx2, aval2);

    // c = x @ embede_w
    k_gemm<128,128,64,false,0><<<128, 256, 0, stream>>>(x, embede_w, c);

    for (int k = 0; k < LL; k++) {
        const int nhop = k + 1;
        // h = relu(c @ Wh[k]) scattered to [B,H,N,D]
        k_gemm<128,256,32,true,1><<<256, 256, 0, stream>>>(c, Wh + (size_t)k*128*256, h);
        // hW = h @ We[k]
        k_gemm<128,128,64,false,0><<<256, 256, 0, stream>>>(h, We + (size_t)k*128*128, hW);
        // split to bf16 hi/lo, then MFMA symmetric e (shared by both branches)
        k_split<<<2048, 256, 0, stream>>>(h, hW, hHi, hLo, wHi, wLo);
        k_esym_mfma<<<dim3(8,8,16), 256, 0, stream>>>(wHi, wLo, hHi, hLo, e);

        for (int br = 0; br < 2; br++) {
            const int*   cidx = (br == 0) ? cidx1 : cidx2;
            const float* aval = (br == 0) ? aval1 : aval2;
            const int*   rcnt = (br == 0) ? rcnt1 : rcnt2;
            const int*   ccnt = (br == 0) ? ccnt1 : ccnt2;
            float*       cb   = (br == 0) ? c1    : c2;

            // sparse softmax over columns
            k_zero_i<<<128, 256, 0, stream>>>(colmax, 32768);  // colmax + colsum
            k_p1<<<4096, 256, 0, stream>>>(e, cidx, rcnt, attv, colmax);
            k_p2<<<4096, 256, 0, stream>>>(cidx, rcnt, attv, colmax, colsum);
            k_p3<<<64, 256, 0, stream>>>(colsum, colmax, ccnt, dinv);
            k_p4<<<4096, 256, 0, stream>>>(cidx, rcnt, aval, dinv, attv);

            // hop 0: az = relu(att@h); beta; z = beta*h + (1-beta)*az
            k_spmm<false><<<4096, 256, 0, stream>>>(attv, cidx, rcnt, h, nullptr, nullptr, az);
            k_beta<<<4096, 256, 0, stream>>>(h, az, Wbw + (size_t)k*256, Wbb + k, beta);
            k_zup<<<2048, 256, 0, stream>>>(h, az, beta, z);
            // hops 1..nhop-1 fused
            float* zA = z; float* zB = z2;
            for (int t = 1; t < nhop; t++) {
                k_spmm<true><<<4096, 256, 0, stream>>>(attv, cidx, rcnt, zA, h, beta, zB);
                float* tmp = zA; zA = zB; zB = tmp;
            }
            // cb = relu(z gathered to [B,N,H*D]) @ Wo[k]
            k_gemm<256,128,64,false,2><<<128, 256, 0, stream>>>(zA, Wo + (size_t)k*256*128, cb);
        }
        k_sub<<<1024, 256, 0, stream>>>(c2, c1, c);
    }

    k_pool<<<8, 128, 0, stream>>>(c, valid, pooled);
    k_fc<128, DFCN, true><<<16, 256, 0, stream>>>(pooled, fc0_w, fc0_b, f0);
    k_fc<DFCN, DFCN, true><<<16, 256, 0, stream>>>(f0, fc1_w, fc1_b, f1);
    k_fc2<<<1, 512, 0, stream>>>(f1, fc2_w, fc2_b, (float*)d_out);
}

// Round 4
// 2664.541 us; speedup vs baseline: 1.5299x; 1.0999x over previous
//
#include <hip/hip_runtime.h>
#include <math.h>

#define BB 8
#define NN 1024
#define DD 128
#define HH 2
#define LL 4
#define DFCN 512

typedef __attribute__((ext_vector_type(8))) short bf16x8;
typedef __attribute__((ext_vector_type(8))) _Float16 f16x8;
typedef __attribute__((ext_vector_type(4))) float f32x4;
typedef unsigned long long u64;
typedef unsigned short ushortT;

// fp32 -> bf16 (RNE) and back
static __device__ __forceinline__ unsigned short f2bf(float f) {
    unsigned u = __float_as_uint(f);
    u += 0x7FFF + ((u >> 16) & 1);
    return (unsigned short)(u >> 16);
}
static __device__ __forceinline__ float bf2f(unsigned short s) {
    return __uint_as_float(((unsigned)s) << 16);
}
// fp32 <-> fp16
static __device__ __forceinline__ unsigned short f2h(float f) {
    _Float16 h = (_Float16)f; return *(unsigned short*)&h;
}
static __device__ __forceinline__ float h2f(unsigned short u) {
    _Float16 h; *(unsigned short*)&h = u; return (float)h;
}

// ---------------------------------------------------------------------------
// Generic small-K GEMM: Y[M,NOUT] = X[M,K] @ W[K,NOUT]
// MODE 0: plain row-major fp32 out
// MODE 1: scatter out [B,N,H*D] -> [B,H,N,D] fp32 + bf16 hi/lo split outs
// MODE 2: gather input [B,H,N,D] -> [B,N,H*D] with relu on load
// MODE 3: row-major out as bf16 hi/lo split only (no fp32)
// ---------------------------------------------------------------------------
template<int K, int NOUT, int TM, bool RELU_OUT, int MODE>
__global__ __launch_bounds__(256) void k_gemm(const float* __restrict__ X,
                                              const float* __restrict__ W,
                                              float* __restrict__ Y,
                                              ushortT* __restrict__ O1,
                                              ushortT* __restrict__ O2) {
    constexpr int KC  = 32;
    constexpr int CT  = NOUT / 4;
    constexpr int RT  = 256 / CT;
    constexpr int RPT = TM / RT;
    __shared__ float Xs[TM][KC];
    __shared__ float Ws[KC][NOUT];
    const int t   = threadIdx.x;
    const int ct  = t % CT, rt = t / CT;
    const int row0 = blockIdx.x * TM;
    float acc[RPT][4];
#pragma unroll
    for (int r = 0; r < RPT; r++) { acc[r][0]=acc[r][1]=acc[r][2]=acc[r][3]=0.f; }

    for (int k0 = 0; k0 < K; k0 += KC) {
        constexpr int NX4 = TM * KC / 4;
#pragma unroll
        for (int p = 0; p < NX4 / 256; p++) {
            int idx = t + p * 256;
            int r = idx / (KC / 4), kg = idx % (KC / 4);
            int m = row0 + r;
            float4 v;
            if (MODE == 2) {
                int b = m / NN, n = m % NN;
                int hh = k0 / DD;
                int d  = (k0 % DD) + kg * 4;
                v = *(const float4*)&X[(((size_t)b * HH + hh) * NN + n) * DD + d];
                v.x = fmaxf(v.x, 0.f); v.y = fmaxf(v.y, 0.f);
                v.z = fmaxf(v.z, 0.f); v.w = fmaxf(v.w, 0.f);
            } else {
                v = *(const float4*)&X[(size_t)m * K + k0 + kg * 4];
            }
            *(float4*)&Xs[r][kg * 4] = v;
        }
        constexpr int NW4 = KC * NOUT / 4;
#pragma unroll
        for (int p = 0; p < NW4 / 256; p++) {
            int idx = t + p * 256;
            int kk = idx / (NOUT / 4), cg = idx % (NOUT / 4);
            *(float4*)&Ws[kk][cg * 4] =
                *(const float4*)&W[(size_t)(k0 + kk) * NOUT + cg * 4];
        }
        __syncthreads();
#pragma unroll
        for (int kk = 0; kk < KC; kk++) {
            float4 wv = *(const float4*)&Ws[kk][ct * 4];
#pragma unroll
            for (int r = 0; r < RPT; r++) {
                float xv = Xs[rt * RPT + r][kk];
                acc[r][0] += xv * wv.x; acc[r][1] += xv * wv.y;
                acc[r][2] += xv * wv.z; acc[r][3] += xv * wv.w;
            }
        }
        __syncthreads();
    }
#pragma unroll
    for (int r = 0; r < RPT; r++) {
        int m = row0 + rt * RPT + r;
        float4 v = make_float4(acc[r][0], acc[r][1], acc[r][2], acc[r][3]);
        if (RELU_OUT) {
            v.x = fmaxf(v.x, 0.f); v.y = fmaxf(v.y, 0.f);
            v.z = fmaxf(v.z, 0.f); v.w = fmaxf(v.w, 0.f);
        }
        if (MODE == 1) {
            int b = m / NN, n = m % NN;
            int o = ct * 4; int hh = o / DD, d = o % DD;
            size_t addr = (((size_t)b * HH + hh) * NN + n) * DD + d;
            *(float4*)&Y[addr] = v;
            ushort4 hi, lo;
            hi.x = f2bf(v.x); lo.x = f2bf(v.x - bf2f(hi.x));
            hi.y = f2bf(v.y); lo.y = f2bf(v.y - bf2f(hi.y));
            hi.z = f2bf(v.z); lo.z = f2bf(v.z - bf2f(hi.z));
            hi.w = f2bf(v.w); lo.w = f2bf(v.w - bf2f(hi.w));
            *(ushort4*)&O1[addr] = hi;
            *(ushort4*)&O2[addr] = lo;
        } else if (MODE == 3) {
            size_t addr = (size_t)m * NOUT + ct * 4;
            ushort4 hi, lo;
            hi.x = f2bf(v.x); lo.x = f2bf(v.x - bf2f(hi.x));
            hi.y = f2bf(v.y); lo.y = f2bf(v.y - bf2f(hi.y));
            hi.z = f2bf(v.z); lo.z = f2bf(v.z - bf2f(hi.z));
            hi.w = f2bf(v.w); lo.w = f2bf(v.w - bf2f(hi.w));
            *(ushort4*)&O1[addr] = hi;
            *(ushort4*)&O2[addr] = lo;
        } else {
            *(float4*)&Y[(size_t)m * NOUT + ct * 4] = v;
        }
    }
}

// ---------------------------------------------------------------------------
// e[j,k] = hW_j.h_k + h_j.hW_k via split-bf16 MFMA (6 terms, lo*lo dropped).
// UNCHANGED from round 3 (verified on HW, absmax 0.0).
// ---------------------------------------------------------------------------
__global__ __launch_bounds__(256) void k_esym_mfma(const ushortT* __restrict__ wHi,
                                                   const ushortT* __restrict__ wLo,
                                                   const ushortT* __restrict__ hHi,
                                                   const ushortT* __restrict__ hLo,
                                                   float* __restrict__ e) {
    __shared__ ushortT sWjHi[128*40], sWjLo[128*40], sHjHi[128*40], sHjLo[128*40];
    __shared__ ushortT sWkHi[128*40], sWkLo[128*40], sHkHi[128*40], sHkLo[128*40];
    const int bh = blockIdx.z;
    const int j0 = blockIdx.y * 128, k0 = blockIdx.x * 128;
    const int t = threadIdx.x;
    const int wave = t >> 6, lane = t & 63;
    const int wr = wave >> 1, wc = wave & 1;
    const int lrow = lane & 15, lg = lane >> 4;

    f32x4 acc[4][4];
#pragma unroll
    for (int m = 0; m < 4; m++)
#pragma unroll
        for (int n = 0; n < 4; n++) {
            acc[m][n][0] = 0.f; acc[m][n][1] = 0.f;
            acc[m][n][2] = 0.f; acc[m][n][3] = 0.f;
        }

    const size_t bhbase = (size_t)bh * NN * DD;

    for (int d0 = 0; d0 < DD; d0 += 32) {
        __syncthreads();
#define STAGE2(SRC, DST, BASE)                                                   \
        {                                                                        \
            _Pragma("unroll")                                                    \
            for (int q = 0; q < 2; q++) {                                        \
                const int u = t + q * 256;                                       \
                const int row = u >> 2, cu = (u & 3) * 8;                        \
                *(uint4*)&DST[row * 40 + cu] =                                   \
                    *(const uint4*)&SRC[bhbase + (size_t)(BASE + row) * DD + d0 + cu]; \
            }                                                                    \
        }
        STAGE2(wHi, sWjHi, j0) STAGE2(wLo, sWjLo, j0)
        STAGE2(hHi, sHjHi, j0) STAGE2(hLo, sHjLo, j0)
        STAGE2(wHi, sWkHi, k0) STAGE2(wLo, sWkLo, k0)
        STAGE2(hHi, sHkHi, k0) STAGE2(hLo, sHkLo, k0)
#undef STAGE2
        __syncthreads();

        bf16x8 a0[4], a1[4], b0[4], b1[4];
#pragma unroll
        for (int m = 0; m < 4; m++) {
            const int off = (wr * 64 + m * 16 + lrow) * 40 + lg * 8;
            a0[m] = *(const bf16x8*)&sWjHi[off];
            a1[m] = *(const bf16x8*)&sWjLo[off];
        }
#pragma unroll
        for (int n = 0; n < 4; n++) {
            const int off = (wc * 64 + n * 16 + lrow) * 40 + lg * 8;
            b0[n] = *(const bf16x8*)&sHkHi[off];
            b1[n] = *(const bf16x8*)&sHkLo[off];
        }
#pragma unroll
        for (int m = 0; m < 4; m++)
#pragma unroll
            for (int n = 0; n < 4; n++) {
                acc[m][n] = __builtin_amdgcn_mfma_f32_16x16x32_bf16(a0[m], b0[n], acc[m][n], 0, 0, 0);
                acc[m][n] = __builtin_amdgcn_mfma_f32_16x16x32_bf16(a0[m], b1[n], acc[m][n], 0, 0, 0);
                acc[m][n] = __builtin_amdgcn_mfma_f32_16x16x32_bf16(a1[m], b0[n], acc[m][n], 0, 0, 0);
            }
#pragma unroll
        for (int m = 0; m < 4; m++) {
            const int off = (wr * 64 + m * 16 + lrow) * 40 + lg * 8;
            a0[m] = *(const bf16x8*)&sHjHi[off];
            a1[m] = *(const bf16x8*)&sHjLo[off];
        }
#pragma unroll
        for (int n = 0; n < 4; n++) {
            const int off = (wc * 64 + n * 16 + lrow) * 40 + lg * 8;
            b0[n] = *(const bf16x8*)&sWkHi[off];
            b1[n] = *(const bf16x8*)&sWkLo[off];
        }
#pragma unroll
        for (int m = 0; m < 4; m++)
#pragma unroll
            for (int n = 0; n < 4; n++) {
                acc[m][n] = __builtin_amdgcn_mfma_f32_16x16x32_bf16(a0[m], b0[n], acc[m][n], 0, 0, 0);
                acc[m][n] = __builtin_amdgcn_mfma_f32_16x16x32_bf16(a0[m], b1[n], acc[m][n], 0, 0, 0);
                acc[m][n] = __builtin_amdgcn_mfma_f32_16x16x32_bf16(a1[m], b0[n], acc[m][n], 0, 0, 0);
            }
    }

#pragma unroll
    for (int m = 0; m < 4; m++)
#pragma unroll
        for (int n = 0; n < 4; n++) {
            const int r = j0 + wr * 64 + m * 16 + lg * 4;
            const int cc = k0 + wc * 64 + n * 16 + lrow;
            float* dst = &e[((size_t)bh * NN + r) * NN + cc];
#pragma unroll
            for (int q = 0; q < 4; q++) dst[(size_t)q * NN] = acc[m][n][q];
        }
}

// ---------------------------------------------------------------------------
// Column nnz bitmask build (atomic-free). bits[b][k][t] bit jj <=> adj[b][64t+jj][k]!=0
// ---------------------------------------------------------------------------
__global__ __launch_bounds__(256) void k_buildT(const float* __restrict__ adj,
                                                u64* __restrict__ bits) {
    const int gid = blockIdx.x * 256 + threadIdx.x;   // 8*16*1024
    const int k  = gid & 1023;
    const int tw = (gid >> 10) & 15;
    const int b  = gid >> 14;
    const float* ac = adj + ((size_t)b << 20) + k;
    u64 w = 0;
#pragma unroll 8
    for (int jj = 0; jj < 64; jj++) {
        if (ac[(size_t)(tw * 64 + jj) << 10] != 0.f) w |= 1ull << jj;
    }
    bits[((size_t)((b << 10) | k)) * 16 + tw] = w;
}

// ---------------------------------------------------------------------------
// Softmax pass A: per (bh,k,chunk of 256 j) partial online max/sum over nnz.
// ---------------------------------------------------------------------------
__global__ __launch_bounds__(256) void k_smA(const float* __restrict__ e,
                                             const u64* __restrict__ bits,
                                             float* __restrict__ pm,
                                             float* __restrict__ ps) {
    const int gid = blockIdx.x * 256 + threadIdx.x;   // 16*4*1024
    const int k  = gid & 1023;
    const int c  = (gid >> 10) & 3;
    const int bh = gid >> 12;
    const int b  = bh >> 1;
    const u64* wb = bits + ((size_t)((b << 10) | k)) * 16 + c * 4;
    const float* ec = e + ((size_t)bh << 20) + k;
    float m = -1e30f, s = 0.f;
#pragma unroll
    for (int tw = 0; tw < 4; tw++) {
        const u64 w = wb[tw];
        const int jbase = c * 256 + tw * 64;
        for (int jj = 0; jj < 64; jj++) {
            const float ev = ec[(size_t)(jbase + jj) << 10];
            if ((w >> jj) & 1) {
                if (ev > m) { s = s * __expf(m - ev) + 1.f; m = ev; }
                else        { s += __expf(ev - m); }
            }
        }
    }
    const int o = ((bh << 10) | k) * 4 + c;
    pm[o] = m; ps[o] = s;
}

// Softmax pass B: combine 4 partials; m=max(0,..); denom += (1024-cnt)exp(-m)
__global__ __launch_bounds__(256) void k_smB(const float* __restrict__ pm,
                                             const float* __restrict__ ps,
                                             const u64* __restrict__ bits,
                                             float* __restrict__ smax,
                                             float* __restrict__ sdinv) {
    const int gid = blockIdx.x * 256 + threadIdx.x;   // 16*1024
    const int k  = gid & 1023;
    const int bh = gid >> 10;
    const int b  = bh >> 1;
    const float4 pmv = *(const float4*)&pm[gid * 4];
    const float4 psv = *(const float4*)&ps[gid * 4];
    const float m = fmaxf(fmaxf(fmaxf(pmv.x, pmv.y), fmaxf(pmv.z, pmv.w)), 0.f);
    const u64* wb = bits + ((size_t)((b << 10) | k)) * 16;
    int cnt = 0;
#pragma unroll
    for (int tw = 0; tw < 16; tw++) cnt += __popcll(wb[tw]);
    float s = psv.x * __expf(pmv.x - m) + psv.y * __expf(pmv.y - m)
            + psv.z * __expf(pmv.z - m) + psv.w * __expf(pmv.w - m);
    s += (float)(NN - cnt) * __expf(-m);
    smax[gid] = m;
    sdinv[gid] = 1.f / s;
}

// Softmax pass C: dense write of f16 att (zeros where masked) — no memset, no atomics.
__global__ __launch_bounds__(256) void k_smC(const float* __restrict__ e,
                                             const u64* __restrict__ bits,
                                             const float* __restrict__ smax,
                                             const float* __restrict__ sdinv,
                                             ushortT* __restrict__ att) {
    const int gid = blockIdx.x * 256 + threadIdx.x;   // 16*4*1024
    const int k  = gid & 1023;
    const int c  = (gid >> 10) & 3;
    const int bh = gid >> 12;
    const int b  = bh >> 1;
    const float m  = smax[(bh << 10) | k];
    const float di = sdinv[(bh << 10) | k];
    const u64* wb = bits + ((size_t)((b << 10) | k)) * 16 + c * 4;
    const float* ec = e + ((size_t)bh << 20) + k;
    ushortT* ac = att + ((size_t)bh << 20) + k;
#pragma unroll
    for (int tw = 0; tw < 4; tw++) {
        const u64 w = wb[tw];
        const int jbase = c * 256 + tw * 64;
        for (int jj = 0; jj < 64; jj++) {
            const int j = jbase + jj;
            const float ev = ec[(size_t)j << 10];
            float v = 0.f;
            if ((w >> jj) & 1) v = __expf(ev - m) * di;
            ac[(size_t)j << 10] = f2h(v);
        }
    }
}

// ---------------------------------------------------------------------------
// Transpose h fp32 [bh][n][d] -> hT f16 [bh][d][n]
// ---------------------------------------------------------------------------
__global__ __launch_bounds__(256) void k_trT(const float* __restrict__ h,
                                             ushortT* __restrict__ hT) {
    __shared__ float tile[64][65];
    const int bh = blockIdx.z;
    const int n0 = blockIdx.x * 64, d0 = blockIdx.y * 64;
    const int t = threadIdx.x;
#pragma unroll
    for (int q = 0; q < 16; q++) {
        const int idx = t + q * 256;
        const int row = idx >> 6, col = idx & 63;
        tile[row][col] = h[(size_t)bh * 131072 + (size_t)(n0 + row) * DD + d0 + col];
    }
    __syncthreads();
#pragma unroll
    for (int q = 0; q < 16; q++) {
        const int idx = t + q * 256;
        const int row = idx >> 6, col = idx & 63;
        hT[(size_t)bh * 131072 + (size_t)(d0 + row) * NN + n0 + col] = f2h(tile[col][row]);
    }
}

// Transpose zT f16 [bh][d][n] -> zfin fp32 [bh][n][d]
__global__ __launch_bounds__(256) void k_fin(const ushortT* __restrict__ zT,
                                             float* __restrict__ zfin) {
    __shared__ float tile[64][65];
    const int bh = blockIdx.z;
    const int n0 = blockIdx.x * 64, d0 = blockIdx.y * 64;
    const int t = threadIdx.x;
#pragma unroll
    for (int q = 0; q < 16; q++) {
        const int idx = t + q * 256;
        const int row = idx >> 6, col = idx & 63;
        tile[row][col] = h2f(zT[(size_t)bh * 131072 + (size_t)(d0 + row) * NN + n0 + col]);
    }
    __syncthreads();
#pragma unroll
    for (int q = 0; q < 16; q++) {
        const int idx = t + q * 256;
        const int row = idx >> 6, col = idx & 63;
        zfin[(size_t)bh * 131072 + (size_t)(n0 + row) * DD + d0 + col] = tile[col][row];
    }
}

// ---------------------------------------------------------------------------
// Dense f16 MFMA hop: out = relu(att @ zin^T-layout), optionally fused beta-mix,
// writing output TRANSPOSED [bh][d][n] directly from the C/D fragment.
// Block: 64 output rows (i) x full D=128, 4 waves in 2x2, K=1024 in 64-chunks.
// ---------------------------------------------------------------------------
template<bool FUSED>
__global__ __launch_bounds__(256) void k_hop(const ushortT* __restrict__ att,
                                             const ushortT* __restrict__ zin,
                                             const ushortT* __restrict__ hT,
                                             const float* __restrict__ beta,
                                             ushortT* __restrict__ zout) {
    __shared__ ushortT sA[64 * 72];
    __shared__ ushortT sB[128 * 72];
    const int bh = blockIdx.y;
    const int i0 = blockIdx.x * 64;
    const int t = threadIdx.x, wave = t >> 6, lane = t & 63;
    const int wr = wave >> 1, wc = wave & 1;
    const int lrow = lane & 15, lg = lane >> 4;
    const ushortT* attb = att + ((size_t)bh << 20);
    const ushortT* zb   = zin + (size_t)bh * 131072;

    f32x4 acc[2][4];
#pragma unroll
    for (int m = 0; m < 2; m++)
#pragma unroll
        for (int n = 0; n < 4; n++) {
            acc[m][n][0]=0.f; acc[m][n][1]=0.f; acc[m][n][2]=0.f; acc[m][n][3]=0.f;
        }

    for (int j0 = 0; j0 < NN; j0 += 64) {
        __syncthreads();
#pragma unroll
        for (int q = 0; q < 2; q++) {
            const int u = t + q * 256;
            const int row = u >> 3, c8 = (u & 7) * 8;
            *(uint4*)&sA[row * 72 + c8] =
                *(const uint4*)&attb[(size_t)(i0 + row) * NN + j0 + c8];
        }
#pragma unroll
        for (int q = 0; q < 4; q++) {
            const int u = t + q * 256;
            const int row = u >> 3, c8 = (u & 7) * 8;
            *(uint4*)&sB[row * 72 + c8] =
                *(const uint4*)&zb[(size_t)row * NN + j0 + c8];
        }
        __syncthreads();
#pragma unroll
        for (int ks = 0; ks < 2; ks++) {
            f16x8 a[2], b[4];
#pragma unroll
            for (int m = 0; m < 2; m++)
                a[m] = *(const f16x8*)&sA[(wr * 32 + m * 16 + lrow) * 72 + ks * 32 + lg * 8];
#pragma unroll
            for (int n = 0; n < 4; n++)
                b[n] = *(const f16x8*)&sB[(wc * 64 + n * 16 + lrow) * 72 + ks * 32 + lg * 8];
#pragma unroll
            for (int m = 0; m < 2; m++)
#pragma unroll
                for (int n = 0; n < 4; n++)
                    acc[m][n] = __builtin_amdgcn_mfma_f32_16x16x32_f16(a[m], b[n], acc[m][n], 0, 0, 0);
        }
    }

    const float* betab = beta + ((size_t)bh << 10);
    const ushortT* hTb = hT + (size_t)bh * 131072;
    ushortT* zo = zout + (size_t)bh * 131072;
#pragma unroll
    for (int m = 0; m < 2; m++)
#pragma unroll
        for (int n = 0; n < 4; n++) {
            const int d = wc * 64 + n * 16 + lrow;
            const int i = i0 + wr * 32 + m * 16 + lg * 4;
            ushort4 o;
            float vq[4];
            if (FUSED) {
                const float4 bev = *(const float4*)&betab[i];
                const ushort4 hv = *(const ushort4*)&hTb[(size_t)d * NN + i];
                vq[0] = bev.x * h2f(hv.x) + (1.f - bev.x) * fmaxf(acc[m][n][0], 0.f);
                vq[1] = bev.y * h2f(hv.y) + (1.f - bev.y) * fmaxf(acc[m][n][1], 0.f);
                vq[2] = bev.z * h2f(hv.z) + (1.f - bev.z) * fmaxf(acc[m][n][2], 0.f);
                vq[3] = bev.w * h2f(hv.w) + (1.f - bev.w) * fmaxf(acc[m][n][3], 0.f);
            } else {
                vq[0] = fmaxf(acc[m][n][0], 0.f); vq[1] = fmaxf(acc[m][n][1], 0.f);
                vq[2] = fmaxf(acc[m][n][2], 0.f); vq[3] = fmaxf(acc[m][n][3], 0.f);
            }
            o.x = f2h(vq[0]); o.y = f2h(vq[1]); o.z = f2h(vq[2]); o.w = f2h(vq[3]);
            *(ushort4*)&zo[(size_t)d * NN + i] = o;
        }
}

// beta = sigmoid(sum_d h*W1 + az*W2 + bb), transposed-layout inputs.
__global__ __launch_bounds__(256) void k_betaT(const ushortT* __restrict__ hT,
                                               const ushortT* __restrict__ azT,
                                               const float* __restrict__ Wbw,
                                               const float* __restrict__ Wbb,
                                               float* __restrict__ beta) {
    const int gid = blockIdx.x * 256 + threadIdx.x;   // 16*1024
    const int n  = gid & 1023;
    const int bh = gid >> 10;
    const ushortT* hp = hT  + (size_t)bh * 131072 + n;
    const ushortT* ap = azT + (size_t)bh * 131072 + n;
    float s = 0.f;
#pragma unroll 16
    for (int d = 0; d < DD; d++)
        s += h2f(hp[(size_t)d << 10]) * Wbw[d] + h2f(ap[(size_t)d << 10]) * Wbw[DD + d];
    beta[gid] = 1.f / (1.f + expf(-(s + Wbb[0])));
}

// zT = beta*hT + (1-beta)*azT (f16 transposed, 8 elems/thread)
__global__ __launch_bounds__(256) void k_zupT(const ushortT* __restrict__ hT,
                                              const ushortT* __restrict__ azT,
                                              const float* __restrict__ beta,
                                              ushortT* __restrict__ zT) {
    const int gid = blockIdx.x * 256 + threadIdx.x;   // 2097152/8
    const size_t base = (size_t)gid * 8;
    const int n0 = (int)(base & 1023);
    const int bh = (int)(base >> 17);
    ushortT hu[8], au[8], ou[8];
    *(uint4*)hu = *(const uint4*)&hT[base];
    *(uint4*)au = *(const uint4*)&azT[base];
    const float4 b0 = *(const float4*)&beta[(bh << 10) + n0];
    const float4 b1 = *(const float4*)&beta[(bh << 10) + n0 + 4];
    const float be[8] = {b0.x, b0.y, b0.z, b0.w, b1.x, b1.y, b1.z, b1.w};
#pragma unroll
    for (int i = 0; i < 8; i++)
        ou[i] = f2h(be[i] * h2f(hu[i]) + (1.f - be[i]) * h2f(au[i]));
    *(uint4*)&zT[base] = *(uint4*)ou;
}

__global__ __launch_bounds__(256) void k_sub(const float* __restrict__ c2,
                                             const float* __restrict__ c1,
                                             float* __restrict__ c) {
    const int g = blockIdx.x * 256 + threadIdx.x;
    const float4 a = ((const float4*)c2)[g];
    const float4 b = ((const float4*)c1)[g];
    ((float4*)c)[g] = make_float4(a.x - b.x, a.y - b.y, a.z - b.z, a.w - b.w);
}

__global__ void k_pool(const float* __restrict__ c, const float* __restrict__ valid,
                       float* __restrict__ pooled) {
    const int b = blockIdx.x, d = threadIdx.x;     // 128 threads
    const float* cb = c + (size_t)b * NN * DD;
    const float* vb = valid + (size_t)b * NN;
    float s = 0.f, sv = 0.f;
    for (int n = 0; n < NN; n++) { float v = vb[n]; s += cb[(size_t)n * DD + d] * v; sv += v; }
    pooled[b * DD + d] = s / sv;
}

template<int K, int NOUT, bool RELU>
__global__ void k_fc(const float* __restrict__ X, const float* __restrict__ W,
                     const float* __restrict__ bias, float* __restrict__ Y) {
    const int gid = blockIdx.x * blockDim.x + threadIdx.x;
    if (gid >= BB * NOUT) return;
    const int b = gid / NOUT, o = gid % NOUT;
    float s = bias[o];
    for (int i = 0; i < K; i++) s += X[(size_t)b * K + i] * W[(size_t)i * NOUT + o];
    Y[gid] = RELU ? fmaxf(s, 0.f) : s;
}

__global__ void k_fc2(const float* __restrict__ X, const float* __restrict__ W,
                      const float* __restrict__ bias, float* __restrict__ out) {
    const int b = threadIdx.x >> 6, lane = threadIdx.x & 63;
    float s = 0.f;
    for (int i = lane; i < DFCN; i += 64) s += X[(size_t)b * DFCN + i] * W[i];
#pragma unroll
    for (int off = 32; off > 0; off >>= 1) s += __shfl_down(s, off);
    if (lane == 0) out[b] = 1.f / (1.f + expf(-(s + bias[0])));
}

// ---------------------------------------------------------------------------
extern "C" void kernel_launch(void* const* d_in, const int* in_sizes, int n_in,
                              void* d_out, int out_size, void* d_ws, size_t ws_size,
                              hipStream_t stream) {
    const float* x        = (const float*)d_in[0];
    const float* adj1     = (const float*)d_in[1];
    const float* adj2     = (const float*)d_in[2];
    const float* valid    = (const float*)d_in[3];
    const float* embede_w = (const float*)d_in[4];
    const float* Wh       = (const float*)d_in[5];
    const float* We       = (const float*)d_in[6];
    const float* Wbw      = (const float*)d_in[7];
    const float* Wbb      = (const float*)d_in[8];
    const float* Wo       = (const float*)d_in[9];
    const float* fc0_w    = (const float*)d_in[10];
    const float* fc0_b    = (const float*)d_in[11];
    const float* fc1_w    = (const float*)d_in[12];
    const float* fc1_b    = (const float*)d_in[13];
    const float* fc2_w    = (const float*)d_in[14];
    const float* fc2_b    = (const float*)d_in[15];

    // ---- workspace carve: ~162 MB (<= proven 164 MB budget) ----
    float* ws = (float*)d_ws;
    float* c      = ws;                          // 1,048,576 f
    float* h      = c      + (size_t)1048576;    // 2,097,152 f
    float* e      = h      + (size_t)2097152;    // 16,777,216 f
    float* c1     = e      + (size_t)16777216;   // 1,048,576 f
    float* c2     = c1     + (size_t)1048576;    // 1,048,576 f
    float* zfin   = c2     + (size_t)1048576;    // 2,097,152 f
    float* beta   = zfin   + (size_t)2097152;    // 16,384 f
    float* pm     = beta   + (size_t)16384;      // 65,536 f
    float* ps     = pm     + (size_t)65536;      // 65,536 f
    float* smax   = ps     + (size_t)65536;      // 16,384 f
    float* sdinv  = smax   + (size_t)16384;      // 16,384 f
    float* pooled = sdinv  + (size_t)16384;      // 1,024 f
    float* f0     = pooled + (size_t)1024;       // 4,096 f
    float* f1     = f0     + (size_t)4096;       // 4,096 f
    ushortT* hHi  = (ushortT*)(f1 + 4096);       // 2,097,152 us each
    ushortT* hLo  = hHi + (size_t)2097152;
    ushortT* wHi  = hLo + (size_t)2097152;
    ushortT* wLo  = wHi + (size_t)2097152;
    ushortT* hT   = wLo + (size_t)2097152;
    ushortT* zTa  = hT  + (size_t)2097152;
    ushortT* zTb  = zTa + (size_t)2097152;       // also serves as azT
    ushortT* att  = zTb + (size_t)2097152;       // 16,777,216 us
    u64* bits1    = (u64*)(att + (size_t)16777216); // 131,072 u64
    u64* bits2    = bits1 + (size_t)131072;

    // column nnz bitmasks (atomic-free, layer-independent)
    k_buildT<<<512, 256, 0, stream>>>(adj1, bits1);
    k_buildT<<<512, 256, 0, stream>>>(adj2, bits2);

    // c = x @ embede_w
    k_gemm<128,128,64,false,0><<<128, 256, 0, stream>>>(x, embede_w, c, nullptr, nullptr);

    for (int k = 0; k < LL; k++) {
        const int nhop = k + 1;
        // h = relu(c @ Wh[k]) -> [B,H,N,D] fp32 + bf16 hi/lo split
        k_gemm<128,256,32,true,1><<<256, 256, 0, stream>>>(c, Wh + (size_t)k*32768, h, hHi, hLo);
        // hW = h @ We[k] -> bf16 hi/lo split directly
        k_gemm<128,128,64,false,3><<<256, 256, 0, stream>>>(h, We + (size_t)k*16384, nullptr, wHi, wLo);
        // hT f16 [bh][d][n]
        k_trT<<<dim3(16,2,16), 256, 0, stream>>>(h, hT);
        // dense symmetric e (split-bf16 MFMA, shared by both branches)
        k_esym_mfma<<<dim3(8,8,16), 256, 0, stream>>>(wHi, wLo, hHi, hLo, e);

        for (int br = 0; br < 2; br++) {
            const u64* bits = (br == 0) ? bits1 : bits2;
            float*     cb   = (br == 0) ? c1    : c2;

            // masked column-softmax -> dense f16 att (no atomics, no memset)
            k_smA<<<256, 256, 0, stream>>>(e, bits, pm, ps);
            k_smB<<<64, 256, 0, stream>>>(pm, ps, bits, smax, sdinv);
            k_smC<<<256, 256, 0, stream>>>(e, bits, smax, sdinv, att);

            // hop 0: azT = relu(att@h)  (B-operand = hT)
            k_hop<false><<<dim3(16,16), 256, 0, stream>>>(att, hT, hT, beta, zTb);
            k_betaT<<<64, 256, 0, stream>>>(hT, zTb, Wbw + (size_t)k*256, Wbb + k, beta);
            k_zupT<<<1024, 256, 0, stream>>>(hT, zTb, beta, zTa);
            // hops 1..nhop-1, fused beta-mix
            ushortT* zA = zTa; ushortT* zB = zTb;
            for (int tpp = 1; tpp < nhop; tpp++) {
                k_hop<true><<<dim3(16,16), 256, 0, stream>>>(att, zA, hT, beta, zB);
                ushortT* tmp = zA; zA = zB; zB = tmp;
            }
            // zfin fp32 [bh][n][d]; cb = relu(zfin gathered) @ Wo[k]
            k_fin<<<dim3(16,2,16), 256, 0, stream>>>(zA, zfin);
            k_gemm<256,128,64,false,2><<<128, 256, 0, stream>>>(zfin, Wo + (size_t)k*32768, cb, nullptr, nullptr);
        }
        k_sub<<<1024, 256, 0, stream>>>(c2, c1, c);
    }

    k_pool<<<8, 128, 0, stream>>>(c, valid, pooled);
    k_fc<128, DFCN, true><<<16, 256, 0, stream>>>(pooled, fc0_w, fc0_b, f0);
    k_fc<DFCN, DFCN, true><<<16, 256, 0, stream>>>(f0, fc1_w, fc1_b, f1);
    k_fc2<<<1, 512, 0, stream>>>(f1, fc2_w, fc2_b, (float*)d_out);
}

// Round 5
// 1542.906 us; speedup vs baseline: 2.6421x; 1.7270x over previous
//
#include <hip/hip_runtime.h>
#include <math.h>

#define BB 8
#define NN 1024
#define DD 128
#define HH 2
#define LL 4
#define DFCN 512

typedef __attribute__((ext_vector_type(8))) short bf16x8;
typedef __attribute__((ext_vector_type(8))) _Float16 f16x8;
typedef __attribute__((ext_vector_type(4))) float f32x4;
typedef unsigned long long u64;
typedef unsigned short ushortT;

// fp32 -> bf16 (RNE) and back
static __device__ __forceinline__ unsigned short f2bf(float f) {
    unsigned u = __float_as_uint(f);
    u += 0x7FFF + ((u >> 16) & 1);
    return (unsigned short)(u >> 16);
}
static __device__ __forceinline__ float bf2f(unsigned short s) {
    return __uint_as_float(((unsigned)s) << 16);
}
// fp32 <-> fp16
static __device__ __forceinline__ unsigned short f2h(float f) {
    _Float16 h = (_Float16)f; return *(unsigned short*)&h;
}
static __device__ __forceinline__ float h2f(unsigned short u) {
    _Float16 h; *(unsigned short*)&h = u; return (float)h;
}

// ---------------------------------------------------------------------------
// Generic small-K GEMM: Y[M,NOUT] = X[M,K] @ W[K,NOUT]
// MODE 0: plain row-major fp32 out
// MODE 1: scatter out [B,N,H*D] -> [B,H,N,D] fp32 + bf16 hi/lo split outs
// MODE 2: gather input [B,H,N,D] -> [B,N,H*D] with relu on load
// MODE 3: row-major out as bf16 hi/lo split only (no fp32)
// ---------------------------------------------------------------------------
template<int K, int NOUT, int TM, bool RELU_OUT, int MODE>
__global__ __launch_bounds__(256) void k_gemm(const float* __restrict__ X,
                                              const float* __restrict__ W,
                                              float* __restrict__ Y,
                                              ushortT* __restrict__ O1,
                                              ushortT* __restrict__ O2) {
    constexpr int KC  = 32;
    constexpr int CT  = NOUT / 4;
    constexpr int RT  = 256 / CT;
    constexpr int RPT = TM / RT;
    __shared__ float Xs[TM][KC];
    __shared__ float Ws[KC][NOUT];
    const int t   = threadIdx.x;
    const int ct  = t % CT, rt = t / CT;
    const int row0 = blockIdx.x * TM;
    float acc[RPT][4];
#pragma unroll
    for (int r = 0; r < RPT; r++) { acc[r][0]=acc[r][1]=acc[r][2]=acc[r][3]=0.f; }

    for (int k0 = 0; k0 < K; k0 += KC) {
        constexpr int NX4 = TM * KC / 4;
#pragma unroll
        for (int p = 0; p < NX4 / 256; p++) {
            int idx = t + p * 256;
            int r = idx / (KC / 4), kg = idx % (KC / 4);
            int m = row0 + r;
            float4 v;
            if (MODE == 2) {
                int b = m / NN, n = m % NN;
                int hh = k0 / DD;
                int d  = (k0 % DD) + kg * 4;
                v = *(const float4*)&X[(((size_t)b * HH + hh) * NN + n) * DD + d];
                v.x = fmaxf(v.x, 0.f); v.y = fmaxf(v.y, 0.f);
                v.z = fmaxf(v.z, 0.f); v.w = fmaxf(v.w, 0.f);
            } else {
                v = *(const float4*)&X[(size_t)m * K + k0 + kg * 4];
            }
            *(float4*)&Xs[r][kg * 4] = v;
        }
        constexpr int NW4 = KC * NOUT / 4;
#pragma unroll
        for (int p = 0; p < NW4 / 256; p++) {
            int idx = t + p * 256;
            int kk = idx / (NOUT / 4), cg = idx % (NOUT / 4);
            *(float4*)&Ws[kk][cg * 4] =
                *(const float4*)&W[(size_t)(k0 + kk) * NOUT + cg * 4];
        }
        __syncthreads();
#pragma unroll
        for (int kk = 0; kk < KC; kk++) {
            float4 wv = *(const float4*)&Ws[kk][ct * 4];
#pragma unroll
            for (int r = 0; r < RPT; r++) {
                float xv = Xs[rt * RPT + r][kk];
                acc[r][0] += xv * wv.x; acc[r][1] += xv * wv.y;
                acc[r][2] += xv * wv.z; acc[r][3] += xv * wv.w;
            }
        }
        __syncthreads();
    }
#pragma unroll
    for (int r = 0; r < RPT; r++) {
        int m = row0 + rt * RPT + r;
        float4 v = make_float4(acc[r][0], acc[r][1], acc[r][2], acc[r][3]);
        if (RELU_OUT) {
            v.x = fmaxf(v.x, 0.f); v.y = fmaxf(v.y, 0.f);
            v.z = fmaxf(v.z, 0.f); v.w = fmaxf(v.w, 0.f);
        }
        if (MODE == 1) {
            int b = m / NN, n = m % NN;
            int o = ct * 4; int hh = o / DD, d = o % DD;
            size_t addr = (((size_t)b * HH + hh) * NN + n) * DD + d;
            *(float4*)&Y[addr] = v;
            ushort4 hi, lo;
            hi.x = f2bf(v.x); lo.x = f2bf(v.x - bf2f(hi.x));
            hi.y = f2bf(v.y); lo.y = f2bf(v.y - bf2f(hi.y));
            hi.z = f2bf(v.z); lo.z = f2bf(v.z - bf2f(hi.z));
            hi.w = f2bf(v.w); lo.w = f2bf(v.w - bf2f(hi.w));
            *(ushort4*)&O1[addr] = hi;
            *(ushort4*)&O2[addr] = lo;
        } else if (MODE == 3) {
            size_t addr = (size_t)m * NOUT + ct * 4;
            ushort4 hi, lo;
            hi.x = f2bf(v.x); lo.x = f2bf(v.x - bf2f(hi.x));
            hi.y = f2bf(v.y); lo.y = f2bf(v.y - bf2f(hi.y));
            hi.z = f2bf(v.z); lo.z = f2bf(v.z - bf2f(hi.z));
            hi.w = f2bf(v.w); lo.w = f2bf(v.w - bf2f(hi.w));
            *(ushort4*)&O1[addr] = hi;
            *(ushort4*)&O2[addr] = lo;
        } else {
            *(float4*)&Y[(size_t)m * NOUT + ct * 4] = v;
        }
    }
}

// ---------------------------------------------------------------------------
// e[j,k] = hW_j.h_k + h_j.hW_k via split-bf16 MFMA (6 terms, lo*lo dropped).
// UNCHANGED (verified on HW).
// ---------------------------------------------------------------------------
__global__ __launch_bounds__(256) void k_esym_mfma(const ushortT* __restrict__ wHi,
                                                   const ushortT* __restrict__ wLo,
                                                   const ushortT* __restrict__ hHi,
                                                   const ushortT* __restrict__ hLo,
                                                   float* __restrict__ e) {
    __shared__ ushortT sWjHi[128*40], sWjLo[128*40], sHjHi[128*40], sHjLo[128*40];
    __shared__ ushortT sWkHi[128*40], sWkLo[128*40], sHkHi[128*40], sHkLo[128*40];
    const int bh = blockIdx.z;
    const int j0 = blockIdx.y * 128, k0 = blockIdx.x * 128;
    const int t = threadIdx.x;
    const int wave = t >> 6, lane = t & 63;
    const int wr = wave >> 1, wc = wave & 1;
    const int lrow = lane & 15, lg = lane >> 4;

    f32x4 acc[4][4];
#pragma unroll
    for (int m = 0; m < 4; m++)
#pragma unroll
        for (int n = 0; n < 4; n++) {
            acc[m][n][0] = 0.f; acc[m][n][1] = 0.f;
            acc[m][n][2] = 0.f; acc[m][n][3] = 0.f;
        }

    const size_t bhbase = (size_t)bh * NN * DD;

    for (int d0 = 0; d0 < DD; d0 += 32) {
        __syncthreads();
#define STAGE2(SRC, DST, BASE)                                                   \
        {                                                                        \
            _Pragma("unroll")                                                    \
            for (int q = 0; q < 2; q++) {                                        \
                const int u = t + q * 256;                                       \
                const int row = u >> 2, cu = (u & 3) * 8;                        \
                *(uint4*)&DST[row * 40 + cu] =                                   \
                    *(const uint4*)&SRC[bhbase + (size_t)(BASE + row) * DD + d0 + cu]; \
            }                                                                    \
        }
        STAGE2(wHi, sWjHi, j0) STAGE2(wLo, sWjLo, j0)
        STAGE2(hHi, sHjHi, j0) STAGE2(hLo, sHjLo, j0)
        STAGE2(wHi, sWkHi, k0) STAGE2(wLo, sWkLo, k0)
        STAGE2(hHi, sHkHi, k0) STAGE2(hLo, sHkLo, k0)
#undef STAGE2
        __syncthreads();

        bf16x8 a0[4], a1[4], b0[4], b1[4];
#pragma unroll
        for (int m = 0; m < 4; m++) {
            const int off = (wr * 64 + m * 16 + lrow) * 40 + lg * 8;
            a0[m] = *(const bf16x8*)&sWjHi[off];
            a1[m] = *(const bf16x8*)&sWjLo[off];
        }
#pragma unroll
        for (int n = 0; n < 4; n++) {
            const int off = (wc * 64 + n * 16 + lrow) * 40 + lg * 8;
            b0[n] = *(const bf16x8*)&sHkHi[off];
            b1[n] = *(const bf16x8*)&sHkLo[off];
        }
#pragma unroll
        for (int m = 0; m < 4; m++)
#pragma unroll
            for (int n = 0; n < 4; n++) {
                acc[m][n] = __builtin_amdgcn_mfma_f32_16x16x32_bf16(a0[m], b0[n], acc[m][n], 0, 0, 0);
                acc[m][n] = __builtin_amdgcn_mfma_f32_16x16x32_bf16(a0[m], b1[n], acc[m][n], 0, 0, 0);
                acc[m][n] = __builtin_amdgcn_mfma_f32_16x16x32_bf16(a1[m], b0[n], acc[m][n], 0, 0, 0);
            }
#pragma unroll
        for (int m = 0; m < 4; m++) {
            const int off = (wr * 64 + m * 16 + lrow) * 40 + lg * 8;
            a0[m] = *(const bf16x8*)&sHjHi[off];
            a1[m] = *(const bf16x8*)&sHjLo[off];
        }
#pragma unroll
        for (int n = 0; n < 4; n++) {
            const int off = (wc * 64 + n * 16 + lrow) * 40 + lg * 8;
            b0[n] = *(const bf16x8*)&sWkHi[off];
            b1[n] = *(const bf16x8*)&sWkLo[off];
        }
#pragma unroll
        for (int m = 0; m < 4; m++)
#pragma unroll
            for (int n = 0; n < 4; n++) {
                acc[m][n] = __builtin_amdgcn_mfma_f32_16x16x32_bf16(a0[m], b0[n], acc[m][n], 0, 0, 0);
                acc[m][n] = __builtin_amdgcn_mfma_f32_16x16x32_bf16(a0[m], b1[n], acc[m][n], 0, 0, 0);
                acc[m][n] = __builtin_amdgcn_mfma_f32_16x16x32_bf16(a1[m], b0[n], acc[m][n], 0, 0, 0);
            }
    }

#pragma unroll
    for (int m = 0; m < 4; m++)
#pragma unroll
        for (int n = 0; n < 4; n++) {
            const int r = j0 + wr * 64 + m * 16 + lg * 4;
            const int cc = k0 + wc * 64 + n * 16 + lrow;
            float* dst = &e[((size_t)bh * NN + r) * NN + cc];
#pragma unroll
            for (int q = 0; q < 4; q++) dst[(size_t)q * NN] = acc[m][n][q];
        }
}

// ---------------------------------------------------------------------------
// Column nnz bitmask build (atomic-free). bits[b][k][t] bit jj <=> adj[b][64t+jj][k]!=0
// ---------------------------------------------------------------------------
__global__ __launch_bounds__(256) void k_buildT(const float* __restrict__ adj,
                                                u64* __restrict__ bits) {
    const int gid = blockIdx.x * 256 + threadIdx.x;   // 8*16*1024
    const int k  = gid & 1023;
    const int tw = (gid >> 10) & 15;
    const int b  = gid >> 14;
    const float* ac = adj + ((size_t)b << 20) + k;
    u64 w = 0;
#pragma unroll 8
    for (int jj = 0; jj < 64; jj++) {
        if (ac[(size_t)(tw * 64 + jj) << 10] != 0.f) w |= 1ull << jj;
    }
    bits[((size_t)((b << 10) | k)) * 16 + tw] = w;
}

// ---------------------------------------------------------------------------
// Softmax pass A: partial online max/sum per (bh, 4-col group, 16-row chunk).
// 262144 threads (4 waves/SIMD), float4 loads, branchless online update.
// m init 0 is exact: every column has masked entries contributing exp(0),
// and pass B takes max(.,0) anyway.
// pm/ps layout: [bh][jc][k] for coalesced pass-B reads.
// ---------------------------------------------------------------------------
__global__ __launch_bounds__(256) void k_smA(const float* __restrict__ e,
                                             const u64* __restrict__ bits,
                                             float* __restrict__ pm,
                                             float* __restrict__ ps) {
    const int gid = blockIdx.x * 256 + threadIdx.x;   // 16*64*256
    const int kg = gid & 255;                          // 4-col group
    const int jc = (gid >> 8) & 63;                    // 16-row chunk
    const int bh = gid >> 14;
    const int b  = bh >> 1;
    const int k4 = kg * 4;
    const int tw = jc >> 2;                            // u64 word index
    const int bo = (jc & 3) * 16;                      // bit offset in word
    u64 w[4];
#pragma unroll
    for (int i = 0; i < 4; i++)
        w[i] = bits[((size_t)((b << 10) | (k4 + i))) * 16 + tw];
    const float* ec = e + ((size_t)bh << 20) + (size_t)(jc * 16) * NN + k4;
    float m[4] = {0.f, 0.f, 0.f, 0.f};
    float s[4] = {0.f, 0.f, 0.f, 0.f};
#pragma unroll
    for (int r = 0; r < 16; r++) {
        const float4 ev = *(const float4*)&ec[(size_t)r * NN];
        const float evs[4] = {ev.x, ev.y, ev.z, ev.w};
#pragma unroll
        for (int i = 0; i < 4; i++) {
            const bool on = (w[i] >> (bo + r)) & 1;
            const float v = on ? evs[i] : 0.f;
            const float mn = fmaxf(m[i], v);
            s[i] = s[i] * __expf(m[i] - mn) + (on ? __expf(v - mn) : 0.f);
            m[i] = mn;
        }
    }
    const size_t o = (((size_t)bh * 64 + jc) << 10) + k4;
    *(float4*)&pm[o] = make_float4(m[0], m[1], m[2], m[3]);
    *(float4*)&ps[o] = make_float4(s[0], s[1], s[2], s[3]);
}

// Softmax pass B: combine 64 partials per column; denom += (1024-cnt)exp(-M).
__global__ __launch_bounds__(256) void k_smB(const float* __restrict__ pm,
                                             const float* __restrict__ ps,
                                             const u64* __restrict__ bits,
                                             float* __restrict__ smax,
                                             float* __restrict__ sdinv) {
    const int gid = blockIdx.x * 256 + threadIdx.x;   // 16*1024
    const int k  = gid & 1023;
    const int bh = gid >> 10;
    const int b  = bh >> 1;
    float M = 0.f, S = 0.f;
    for (int jc = 0; jc < 64; jc++) {
        const size_t o = (((size_t)bh * 64 + jc) << 10) + k;
        const float pmv = pm[o], psv = ps[o];
        const float mn = fmaxf(M, pmv);
        S = S * __expf(M - mn) + psv * __expf(pmv - mn);
        M = mn;
    }
    const u64* wb = bits + ((size_t)((b << 10) | k)) * 16;
    int cnt = 0;
#pragma unroll
    for (int tw = 0; tw < 16; tw++) cnt += __popcll(wb[tw]);
    S += (float)(NN - cnt) * __expf(-M);
    smax[gid] = M;
    sdinv[gid] = 1.f / S;
}

// Softmax pass C: dense f16 att write (zeros where masked). float4 in, ushort4 out.
__global__ __launch_bounds__(256) void k_smC(const float* __restrict__ e,
                                             const u64* __restrict__ bits,
                                             const float* __restrict__ smax,
                                             const float* __restrict__ sdinv,
                                             ushortT* __restrict__ att) {
    const int gid = blockIdx.x * 256 + threadIdx.x;   // 16*64*256
    const int kg = gid & 255;
    const int jc = (gid >> 8) & 63;
    const int bh = gid >> 14;
    const int b  = bh >> 1;
    const int k4 = kg * 4;
    const int tw = jc >> 2;
    const int bo = (jc & 3) * 16;
    u64 w[4];
#pragma unroll
    for (int i = 0; i < 4; i++)
        w[i] = bits[((size_t)((b << 10) | (k4 + i))) * 16 + tw];
    const float4 m4 = *(const float4*)&smax[(bh << 10) + k4];
    const float4 d4 = *(const float4*)&sdinv[(bh << 10) + k4];
    const float ms[4] = {m4.x, m4.y, m4.z, m4.w};
    const float ds[4] = {d4.x, d4.y, d4.z, d4.w};
    const float* ec = e + ((size_t)bh << 20) + (size_t)(jc * 16) * NN + k4;
    ushortT* ac = att + ((size_t)bh << 20) + (size_t)(jc * 16) * NN + k4;
#pragma unroll
    for (int r = 0; r < 16; r++) {
        const float4 ev = *(const float4*)&ec[(size_t)r * NN];
        const float evs[4] = {ev.x, ev.y, ev.z, ev.w};
        ushort4 o;
        ushortT os[4];
#pragma unroll
        for (int i = 0; i < 4; i++) {
            const bool on = (w[i] >> (bo + r)) & 1;
            os[i] = f2h(on ? __expf(evs[i] - ms[i]) * ds[i] : 0.f);
        }
        o.x = os[0]; o.y = os[1]; o.z = os[2]; o.w = os[3];
        *(ushort4*)&ac[(size_t)r * NN] = o;
    }
}

// ---------------------------------------------------------------------------
// Transpose h fp32 [bh][n][d] -> hT f16 [bh][d][n]
// ---------------------------------------------------------------------------
__global__ __launch_bounds__(256) void k_trT(const float* __restrict__ h,
                                             ushortT* __restrict__ hT) {
    __shared__ float tile[64][65];
    const int bh = blockIdx.z;
    const int n0 = blockIdx.x * 64, d0 = blockIdx.y * 64;
    const int t = threadIdx.x;
#pragma unroll
    for (int q = 0; q < 16; q++) {
        const int idx = t + q * 256;
        const int row = idx >> 6, col = idx & 63;
        tile[row][col] = h[(size_t)bh * 131072 + (size_t)(n0 + row) * DD + d0 + col];
    }
    __syncthreads();
#pragma unroll
    for (int q = 0; q < 16; q++) {
        const int idx = t + q * 256;
        const int row = idx >> 6, col = idx & 63;
        hT[(size_t)bh * 131072 + (size_t)(d0 + row) * NN + n0 + col] = f2h(tile[col][row]);
    }
}

// Transpose zT f16 [bh][d][n] -> zfin fp32 [bh][n][d]
__global__ __launch_bounds__(256) void k_fin(const ushortT* __restrict__ zT,
                                             float* __restrict__ zfin) {
    __shared__ float tile[64][65];
    const int bh = blockIdx.z;
    const int n0 = blockIdx.x * 64, d0 = blockIdx.y * 64;
    const int t = threadIdx.x;
#pragma unroll
    for (int q = 0; q < 16; q++) {
        const int idx = t + q * 256;
        const int row = idx >> 6, col = idx & 63;
        tile[row][col] = h2f(zT[(size_t)bh * 131072 + (size_t)(d0 + row) * NN + n0 + col]);
    }
    __syncthreads();
#pragma unroll
    for (int q = 0; q < 16; q++) {
        const int idx = t + q * 256;
        const int row = idx >> 6, col = idx & 63;
        zfin[(size_t)bh * 131072 + (size_t)(n0 + row) * DD + d0 + col] = tile[col][row];
    }
}

// ---------------------------------------------------------------------------
// Dense f16 MFMA hop: out = relu(att @ zin^T-layout), optionally fused beta-mix,
// writing output TRANSPOSED [bh][d][n] directly from the C/D fragment.
// ---------------------------------------------------------------------------
template<bool FUSED>
__global__ __launch_bounds__(256) void k_hop(const ushortT* __restrict__ att,
                                             const ushortT* __restrict__ zin,
                                             const ushortT* __restrict__ hT,
                                             const float* __restrict__ beta,
                                             ushortT* __restrict__ zout) {
    __shared__ ushortT sA[64 * 72];
    __shared__ ushortT sB[128 * 72];
    const int bh = blockIdx.y;
    const int i0 = blockIdx.x * 64;
    const int t = threadIdx.x, wave = t >> 6, lane = t & 63;
    const int wr = wave >> 1, wc = wave & 1;
    const int lrow = lane & 15, lg = lane >> 4;
    const ushortT* attb = att + ((size_t)bh << 20);
    const ushortT* zb   = zin + (size_t)bh * 131072;

    f32x4 acc[2][4];
#pragma unroll
    for (int m = 0; m < 2; m++)
#pragma unroll
        for (int n = 0; n < 4; n++) {
            acc[m][n][0]=0.f; acc[m][n][1]=0.f; acc[m][n][2]=0.f; acc[m][n][3]=0.f;
        }

    for (int j0 = 0; j0 < NN; j0 += 64) {
        __syncthreads();
#pragma unroll
        for (int q = 0; q < 2; q++) {
            const int u = t + q * 256;
            const int row = u >> 3, c8 = (u & 7) * 8;
            *(uint4*)&sA[row * 72 + c8] =
                *(const uint4*)&attb[(size_t)(i0 + row) * NN + j0 + c8];
        }
#pragma unroll
        for (int q = 0; q < 4; q++) {
            const int u = t + q * 256;
            const int row = u >> 3, c8 = (u & 7) * 8;
            *(uint4*)&sB[row * 72 + c8] =
                *(const uint4*)&zb[(size_t)row * NN + j0 + c8];
        }
        __syncthreads();
#pragma unroll
        for (int ks = 0; ks < 2; ks++) {
            f16x8 a[2], b[4];
#pragma unroll
            for (int m = 0; m < 2; m++)
                a[m] = *(const f16x8*)&sA[(wr * 32 + m * 16 + lrow) * 72 + ks * 32 + lg * 8];
#pragma unroll
            for (int n = 0; n < 4; n++)
                b[n] = *(const f16x8*)&sB[(wc * 64 + n * 16 + lrow) * 72 + ks * 32 + lg * 8];
#pragma unroll
            for (int m = 0; m < 2; m++)
#pragma unroll
                for (int n = 0; n < 4; n++)
                    acc[m][n] = __builtin_amdgcn_mfma_f32_16x16x32_f16(a[m], b[n], acc[m][n], 0, 0, 0);
        }
    }

    const float* betab = beta + ((size_t)bh << 10);
    const ushortT* hTb = hT + (size_t)bh * 131072;
    ushortT* zo = zout + (size_t)bh * 131072;
#pragma unroll
    for (int m = 0; m < 2; m++)
#pragma unroll
        for (int n = 0; n < 4; n++) {
            const int d = wc * 64 + n * 16 + lrow;
            const int i = i0 + wr * 32 + m * 16 + lg * 4;
            ushort4 o;
            float vq[4];
            if (FUSED) {
                const float4 bev = *(const float4*)&betab[i];
                const ushort4 hv = *(const ushort4*)&hTb[(size_t)d * NN + i];
                vq[0] = bev.x * h2f(hv.x) + (1.f - bev.x) * fmaxf(acc[m][n][0], 0.f);
                vq[1] = bev.y * h2f(hv.y) + (1.f - bev.y) * fmaxf(acc[m][n][1], 0.f);
                vq[2] = bev.z * h2f(hv.z) + (1.f - bev.z) * fmaxf(acc[m][n][2], 0.f);
                vq[3] = bev.w * h2f(hv.w) + (1.f - bev.w) * fmaxf(acc[m][n][3], 0.f);
            } else {
                vq[0] = fmaxf(acc[m][n][0], 0.f); vq[1] = fmaxf(acc[m][n][1], 0.f);
                vq[2] = fmaxf(acc[m][n][2], 0.f); vq[3] = fmaxf(acc[m][n][3], 0.f);
            }
            o.x = f2h(vq[0]); o.y = f2h(vq[1]); o.z = f2h(vq[2]); o.w = f2h(vq[3]);
            *(ushort4*)&zo[(size_t)d * NN + i] = o;
        }
}

// beta = sigmoid(sum_d h*W1 + az*W2 + bb), transposed-layout inputs.
__global__ __launch_bounds__(256) void k_betaT(const ushortT* __restrict__ hT,
                                               const ushortT* __restrict__ azT,
                                               const float* __restrict__ Wbw,
                                               const float* __restrict__ Wbb,
                                               float* __restrict__ beta) {
    const int gid = blockIdx.x * 256 + threadIdx.x;   // 16*1024
    const int n  = gid & 1023;
    const int bh = gid >> 10;
    const ushortT* hp = hT  + (size_t)bh * 131072 + n;
    const ushortT* ap = azT + (size_t)bh * 131072 + n;
    float s = 0.f;
#pragma unroll 16
    for (int d = 0; d < DD; d++)
        s += h2f(hp[(size_t)d << 10]) * Wbw[d] + h2f(ap[(size_t)d << 10]) * Wbw[DD + d];
    beta[gid] = 1.f / (1.f + expf(-(s + Wbb[0])));
}

// zT = beta*hT + (1-beta)*azT (f16 transposed, 8 elems/thread)
__global__ __launch_bounds__(256) void k_zupT(const ushortT* __restrict__ hT,
                                              const ushortT* __restrict__ azT,
                                              const float* __restrict__ beta,
                                              ushortT* __restrict__ zT) {
    const int gid = blockIdx.x * 256 + threadIdx.x;   // 2097152/8
    const size_t base = (size_t)gid * 8;
    const int n0 = (int)(base & 1023);
    const int bh = (int)(base >> 17);
    ushortT hu[8], au[8], ou[8];
    *(uint4*)hu = *(const uint4*)&hT[base];
    *(uint4*)au = *(const uint4*)&azT[base];
    const float4 b0 = *(const float4*)&beta[(bh << 10) + n0];
    const float4 b1 = *(const float4*)&beta[(bh << 10) + n0 + 4];
    const float be[8] = {b0.x, b0.y, b0.z, b0.w, b1.x, b1.y, b1.z, b1.w};
#pragma unroll
    for (int i = 0; i < 8; i++)
        ou[i] = f2h(be[i] * h2f(hu[i]) + (1.f - be[i]) * h2f(au[i]));
    *(uint4*)&zT[base] = *(uint4*)ou;
}

__global__ __launch_bounds__(256) void k_sub(const float* __restrict__ c2,
                                             const float* __restrict__ c1,
                                             float* __restrict__ c) {
    const int g = blockIdx.x * 256 + threadIdx.x;
    const float4 a = ((const float4*)c2)[g];
    const float4 b = ((const float4*)c1)[g];
    ((float4*)c)[g] = make_float4(a.x - b.x, a.y - b.y, a.z - b.z, a.w - b.w);
}

__global__ void k_pool(const float* __restrict__ c, const float* __restrict__ valid,
                       float* __restrict__ pooled) {
    const int b = blockIdx.x, d = threadIdx.x;     // 128 threads
    const float* cb = c + (size_t)b * NN * DD;
    const float* vb = valid + (size_t)b * NN;
    float s = 0.f, sv = 0.f;
    for (int n = 0; n < NN; n++) { float v = vb[n]; s += cb[(size_t)n * DD + d] * v; sv += v; }
    pooled[b * DD + d] = s / sv;
}

template<int K, int NOUT, bool RELU>
__global__ void k_fc(const float* __restrict__ X, const float* __restrict__ W,
                     const float* __restrict__ bias, float* __restrict__ Y) {
    const int gid = blockIdx.x * blockDim.x + threadIdx.x;
    if (gid >= BB * NOUT) return;
    const int b = gid / NOUT, o = gid % NOUT;
    float s = bias[o];
    for (int i = 0; i < K; i++) s += X[(size_t)b * K + i] * W[(size_t)i * NOUT + o];
    Y[gid] = RELU ? fmaxf(s, 0.f) : s;
}

__global__ void k_fc2(const float* __restrict__ X, const float* __restrict__ W,
                      const float* __restrict__ bias, float* __restrict__ out) {
    const int b = threadIdx.x >> 6, lane = threadIdx.x & 63;
    float s = 0.f;
    for (int i = lane; i < DFCN; i += 64) s += X[(size_t)b * DFCN + i] * W[i];
#pragma unroll
    for (int off = 32; off > 0; off >>= 1) s += __shfl_down(s, off);
    if (lane == 0) out[b] = 1.f / (1.f + expf(-(s + bias[0])));
}

// ---------------------------------------------------------------------------
extern "C" void kernel_launch(void* const* d_in, const int* in_sizes, int n_in,
                              void* d_out, int out_size, void* d_ws, size_t ws_size,
                              hipStream_t stream) {
    const float* x        = (const float*)d_in[0];
    const float* adj1     = (const float*)d_in[1];
    const float* adj2     = (const float*)d_in[2];
    const float* valid    = (const float*)d_in[3];
    const float* embede_w = (const float*)d_in[4];
    const float* Wh       = (const float*)d_in[5];
    const float* We       = (const float*)d_in[6];
    const float* Wbw      = (const float*)d_in[7];
    const float* Wbb      = (const float*)d_in[8];
    const float* Wo       = (const float*)d_in[9];
    const float* fc0_w    = (const float*)d_in[10];
    const float* fc0_b    = (const float*)d_in[11];
    const float* fc1_w    = (const float*)d_in[12];
    const float* fc1_b    = (const float*)d_in[13];
    const float* fc2_w    = (const float*)d_in[14];
    const float* fc2_b    = (const float*)d_in[15];

    // ---- workspace carve: ~162 MB ----
    float* ws = (float*)d_ws;
    float* c      = ws;                          // 1,048,576 f
    float* h      = c      + (size_t)1048576;    // 2,097,152 f
    float* e      = h      + (size_t)2097152;    // 16,777,216 f
    float* c1     = e      + (size_t)16777216;   // 1,048,576 f
    float* c2     = c1     + (size_t)1048576;    // 1,048,576 f
    float* zfin   = c2     + (size_t)1048576;    // 2,097,152 f
    float* beta   = zfin   + (size_t)2097152;    // 16,384 f
    float* pm     = beta   + (size_t)16384;      // 1,048,576 f ([bh][64][1024])
    float* ps     = pm     + (size_t)1048576;    // 1,048,576 f
    float* smax   = ps     + (size_t)1048576;    // 16,384 f
    float* sdinv  = smax   + (size_t)16384;      // 16,384 f
    float* pooled = sdinv  + (size_t)16384;      // 1,024 f
    float* f0     = pooled + (size_t)1024;       // 4,096 f
    float* f1     = f0     + (size_t)4096;       // 4,096 f
    ushortT* hHi  = (ushortT*)(f1 + 4096);       // 2,097,152 us each
    ushortT* hLo  = hHi + (size_t)2097152;
    ushortT* wHi  = hLo + (size_t)2097152;
    ushortT* wLo  = wHi + (size_t)2097152;
    ushortT* hT   = wLo + (size_t)2097152;
    ushortT* zTa  = hT  + (size_t)2097152;
    ushortT* zTb  = zTa + (size_t)2097152;       // also serves as azT
    ushortT* att  = zTb + (size_t)2097152;       // 16,777,216 us
    u64* bits1    = (u64*)(att + (size_t)16777216); // 131,072 u64
    u64* bits2    = bits1 + (size_t)131072;

    // column nnz bitmasks (atomic-free, layer-independent)
    k_buildT<<<512, 256, 0, stream>>>(adj1, bits1);
    k_buildT<<<512, 256, 0, stream>>>(adj2, bits2);

    // c = x @ embede_w
    k_gemm<128,128,64,false,0><<<128, 256, 0, stream>>>(x, embede_w, c, nullptr, nullptr);

    for (int k = 0; k < LL; k++) {
        const int nhop = k + 1;
        // h = relu(c @ Wh[k]) -> [B,H,N,D] fp32 + bf16 hi/lo split
        k_gemm<128,256,32,true,1><<<256, 256, 0, stream>>>(c, Wh + (size_t)k*32768, h, hHi, hLo);
        // hW = h @ We[k] -> bf16 hi/lo split directly
        k_gemm<128,128,64,false,3><<<256, 256, 0, stream>>>(h, We + (size_t)k*16384, nullptr, wHi, wLo);
        // hT f16 [bh][d][n]
        k_trT<<<dim3(16,2,16), 256, 0, stream>>>(h, hT);
        // dense symmetric e (split-bf16 MFMA, shared by both branches)
        k_esym_mfma<<<dim3(8,8,16), 256, 0, stream>>>(wHi, wLo, hHi, hLo, e);

        for (int br = 0; br < 2; br++) {
            const u64* bits = (br == 0) ? bits1 : bits2;
            float*     cb   = (br == 0) ? c1    : c2;

            // masked column-softmax -> dense f16 att (no atomics, no memset)
            k_smA<<<1024, 256, 0, stream>>>(e, bits, pm, ps);
            k_smB<<<64, 256, 0, stream>>>(pm, ps, bits, smax, sdinv);
            k_smC<<<1024, 256, 0, stream>>>(e, bits, smax, sdinv, att);

            // hop 0: azT = relu(att@h)  (B-operand = hT)
            k_hop<false><<<dim3(16,16), 256, 0, stream>>>(att, hT, hT, beta, zTb);
            k_betaT<<<64, 256, 0, stream>>>(hT, zTb, Wbw + (size_t)k*256, Wbb + k, beta);
            k_zupT<<<1024, 256, 0, stream>>>(hT, zTb, beta, zTa);
            // hops 1..nhop-1, fused beta-mix
            ushortT* zA = zTa; ushortT* zB = zTb;
            for (int tpp = 1; tpp < nhop; tpp++) {
                k_hop<true><<<dim3(16,16), 256, 0, stream>>>(att, zA, hT, beta, zB);
                ushortT* tmp = zA; zA = zB; zB = tmp;
            }
            // zfin fp32 [bh][n][d]; cb = relu(zfin gathered) @ Wo[k]
            k_fin<<<dim3(16,2,16), 256, 0, stream>>>(zA, zfin);
            k_gemm<256,128,64,false,2><<<128, 256, 0, stream>>>(zfin, Wo + (size_t)k*32768, cb, nullptr, nullptr);
        }
        k_sub<<<1024, 256, 0, stream>>>(c2, c1, c);
    }

    k_pool<<<8, 128, 0, stream>>>(c, valid, pooled);
    k_fc<128, DFCN, true><<<16, 256, 0, stream>>>(pooled, fc0_w, fc0_b, f0);
    k_fc<DFCN, DFCN, true><<<16, 256, 0, stream>>>(f0, fc1_w, fc1_b, f1);
    k_fc2<<<1, 512, 0, stream>>>(f1, fc2_w, fc2_b, (float*)d_out);
}